// Round 7
// baseline (2039.197 us; speedup 1.0000x reference)
//
#include <hip/hip_runtime.h>
#include <math.h>

#define BB 128
#define NN 128
#define KK 16
#define MEDGE (BB*NN*KK)   // 262144 edges
#define MNODE (BB*NN)      // 16384 nodes

typedef __bf16 bf16x8 __attribute__((ext_vector_type(8)));
typedef float  floatx4 __attribute__((ext_vector_type(4)));
typedef unsigned short u16;
typedef u16 ushort8_alias __attribute__((ext_vector_type(8)));

// ---------------------------------------------------------------- utilities

__device__ __forceinline__ unsigned ord32(float f) {
  unsigned u = __float_as_uint(f);
  return (u & 0x80000000u) ? ~u : (u | 0x80000000u);
}

__device__ __forceinline__ u16 bf16_rne_bits(float x) {
  unsigned u = __float_as_uint(x);
  return (u16)((u + 0x7FFF + ((u >> 16) & 1)) >> 16);
}

// ---------------------------------------------------------------- fused kNN (dist + ballot-radix select)
template<int C>
__global__ __launch_bounds__(256) void knn_fused(const float* __restrict__ x,
                                                 int* __restrict__ idx) {
  constexpr int S = C + 2;
  constexpr int DS = NN + 2;
  constexpr int XSZ = (NN * S > 64 * DS) ? NN * S : 64 * DS;   // union sizing
  __shared__ float xs[XSZ];   // x staging, then reused as Dl[64 * DS]
  __shared__ float sq[NN];
  int b = blockIdx.x >> 1, half = blockIdx.x & 1;
  const float* xb = x + (size_t)b * NN * C;
  int tid = threadIdx.x;

  for (int t = tid; t < NN * C; t += 256) {
    int row = t / C, c = t - row * C;
    xs[row * S + c] = xb[t];
  }
  __syncthreads();
  if (tid < NN) {
    const float* xr = xs + tid * S;
    float s = 0.f;
    for (int c = 0; c < C; ++c) s = fmaf(xr[c], xr[c], s);
    sq[tid] = s;
  }
  __syncthreads();

  // dist: 64 rows x 128 cols; thread = 8 rows x 4 cols (in registers)
  int rg = tid >> 5, cg = tid & 31;
  int r0 = half * 64 + rg * 8;
  float acc[8][4];
#pragma unroll
  for (int i = 0; i < 8; ++i)
#pragma unroll
    for (int j = 0; j < 4; ++j) acc[i][j] = 0.f;
  for (int c = 0; c < C; c += 2) {
    float2 av[8], bv[4];
#pragma unroll
    for (int i = 0; i < 8; ++i) av[i] = *(const float2*)&xs[(r0 + i) * S + c];
#pragma unroll
    for (int j = 0; j < 4; ++j) bv[j] = *(const float2*)&xs[(cg + 32 * j) * S + c];
#pragma unroll
    for (int i = 0; i < 8; ++i)
#pragma unroll
      for (int j = 0; j < 4; ++j) {
        acc[i][j] = fmaf(av[i].x, bv[j].x, acc[i][j]);
        acc[i][j] = fmaf(av[i].y, bv[j].y, acc[i][j]);
      }
  }
  float dv[8][4];
#pragma unroll
  for (int i = 0; i < 8; ++i) {
    float sn = sq[r0 + i];
#pragma unroll
    for (int j = 0; j < 4; ++j) dv[i][j] = sn - 2.f * acc[i][j] + sq[cg + 32 * j];
  }
  __syncthreads();  // all reads of xs complete
  float* Dl = xs;
#pragma unroll
  for (int i = 0; i < 8; ++i)
#pragma unroll
    for (int j = 0; j < 4; ++j)
      Dl[(rg * 8 + i) * DS + (cg + 32 * j)] = dv[i][j];
  __syncthreads();

  int lane = tid & 63, wv = tid >> 6;
  unsigned long long lmaskLT = (1ull << lane) - 1ull;   // bits below my lane
  for (int t = 0; t < 16; ++t) {
    int lr = wv * 16 + t;
    int nd = b * NN + half * 64 + lr;
    unsigned k0 = ord32(Dl[lr * DS + lane]);
    unsigned k1 = ord32(Dl[lr * DS + lane + 64]);
    int* out = idx + (size_t)nd * KK;

    // radix search: find the (32-bd)-bit prefix of the 16th-smallest key
    unsigned prefix = 0;
    int remaining = KK;      // how many still to take inside current group
    int G = 2 * 64;          // current prefix-group size
    int bd = 32;
    while (bd > 0) {
      --bd;
      unsigned pp = prefix << 1;
      bool m0 = (k0 >> bd) == pp;
      bool m1 = (k1 >> bd) == pp;
      int cnt0 = __popcll(__ballot(m0)) + __popcll(__ballot(m1));
      if (remaining <= cnt0) { prefix = pp; G = cnt0; }
      else                   { remaining -= cnt0; prefix = pp | 1; G -= cnt0; }
      if (G == remaining) break;   // whole group selected; low bits irrelevant
    }

    // emit: all keys strictly below the group + lowest-index `remaining` ties
    bool lt0 = (k0 >> bd) < prefix, eq0 = (k0 >> bd) == prefix;
    bool lt1 = (k1 >> bd) < prefix, eq1 = (k1 >> bd) == prefix;
    unsigned long long e0 = __ballot(eq0), e1 = __ballot(eq1);
    int c0 = __popcll(e0);
    int r0t = __popcll(e0 & lmaskLT);
    int r1t = c0 + __popcll(e1 & lmaskLT);
    bool s0 = lt0 || (eq0 && (r0t < remaining));
    bool s1 = lt1 || (eq1 && (r1t < remaining));
    unsigned long long S0 = __ballot(s0), S1 = __ballot(s1);
    int pos0 = __popcll(S0 & lmaskLT);
    int pos1 = __popcll(S0) + __popcll(S1 & lmaskLT);
    if (s0) out[pos0] = lane;
    if (s1) out[pos1] = lane + 64;
  }
}

// ---------------------------------------------------------------- node GEMM (scalar, layer-1 only)
__global__ __launch_bounds__(256) void node_gemm(const float* __restrict__ x,
                                                 const float* __restrict__ W,
                                                 float* __restrict__ p, float* __restrict__ q,
                                                 int Cin, int Cout) {
  int c = threadIdx.x;
  __shared__ float xr[128];
  for (int r = 0; r < 8; ++r) {
    int row = blockIdx.x * 8 + r;
    __syncthreads();
    for (int i = c; i < Cin; i += blockDim.x) xr[i] = x[(size_t)row * Cin + i];
    __syncthreads();
    float a = 0.f, qv = 0.f;
    for (int i = 0; i < Cin; ++i) {
      float xv = xr[i];
      a  = fmaf(xv, W[i * Cout + c], a);
      qv = fmaf(xv, W[(Cin + i) * Cout + c], qv);
    }
    p[(size_t)row * Cout + c] = a - qv;
    q[(size_t)row * Cout + c] = qv;
  }
}

// ---------------------------------------------------------------- weight packing (device bodies)
template<int K, int N>
__device__ __forceinline__ void pack1_body(const float* __restrict__ W1,
                                           u16* __restrict__ Wh, u16* __restrict__ Wl,
                                           int blk, int tidx) {
  int t = blk * 256 + tidx;
  if (t >= K * N) return;
  constexpr int C = N / 2;
  constexpr int NT = N / 16;
  int j = t & 7, lane = (t >> 3) & 63, tile = t >> 9;
  int nt = tile % NT, kt = tile / NT;
  int row = kt * 32 + (lane >> 4) * 8 + j;
  int col = nt * 16 + (lane & 15);
  float w;
  if (col < C) w = W1[row * C + col] - W1[(K + row) * C + col];
  else         w = W1[(K + row) * C + (col - C)];
  u16 h = bf16_rne_bits(w);
  float hf = __uint_as_float(((unsigned)h) << 16);
  Wh[t] = h;
  Wl[t] = bf16_rne_bits(w - hf);
}

template<int C>
__device__ __forceinline__ void pack2_body(const float* __restrict__ W,
                                           u16* __restrict__ Wh, u16* __restrict__ Wl,
                                           int blk, int tidx) {
  int t = blk * 256 + tidx;
  if (t >= C * C) return;
  constexpr int NT = C / 16;
  int j = t & 7, lane = (t >> 3) & 63, tile = t >> 9;
  int nt = tile % NT, kt = tile / NT;
  int row = kt * 32 + (lane >> 4) * 8 + j;
  int col = nt * 16 + (lane & 15);
  float w = W[row * C + col];
  u16 h = bf16_rne_bits(w);
  float hf = __uint_as_float(((unsigned)h) << 16);
  Wh[t] = h;
  Wl[t] = bf16_rne_bits(w - hf);
}

// one dispatch packs all 5 weight matrices into per-layer buffers
__global__ __launch_bounds__(256) void pack_all(
    const float* __restrict__ w12, const float* __restrict__ w22, const float* __restrict__ w32,
    const float* __restrict__ w21, const float* __restrict__ w31,
    u16* h12, u16* l12, u16* h22, u16* l22, u16* h32, u16* l32,
    u16* h21, u16* l21, u16* h31, u16* l31) {
  int blk = blockIdx.x, tidx = threadIdx.x;
  if (blk < 16)        pack2_body<64 >(w12, h12, l12, blk,        tidx);
  else if (blk < 80)   pack2_body<128>(w22, h22, l22, blk - 16,   tidx);
  else if (blk < 336)  pack2_body<256>(w32, h32, l32, blk - 80,   tidx);
  else if (blk < 400)  pack1_body<64, 256>(w21, h21, l21, blk - 336, tidx);
  else                 pack1_body<128, 512>(w31, h31, l31, blk - 400, tidx);
}

// ---------------------------------------------------------------- node GEMM v2 (v9-style, VGPR staging)
template<int K, int N>
__global__ __launch_bounds__(512, 4) void node_gemm_v2(
    const float* __restrict__ x, const u16* __restrict__ Wh, const u16* __restrict__ Wl,
    float* __restrict__ p, float* __restrict__ q) {
  constexpr int C = N / 2;
  constexpr int KT = K / 32;
  constexpr int NT = N / 16;
  constexpr int NCOL = 64, NTS = 4;
  constexpr int NSLICE = N / 64;
  constexpr int CCH = KT * NTS * 2 * 64;
  __shared__ __align__(16) u16 Bst[CCH * 8];

  int tid = threadIdx.x, lane = tid & 63, wv = tid >> 6;
  int r = lane & 15, kseg = lane >> 4;
  int g = blockIdx.x / NSLICE, slice = blockIdx.x % NSLICE;
  int rowBase = g * 128 + wv * 16;
  const float* xr = x + (size_t)(rowBase + r) * K;

  for (int i = tid; i < CCH; i += 512) {
    int c = i & 63, h = (i >> 6) & 1, rest = i >> 7;
    int nt = rest % NTS, kt = rest / NTS;
    const ushort8_alias* src = h ? (const ushort8_alias*)Wl : (const ushort8_alias*)Wh;
    ((ushort8_alias*)Bst)[i] = src[((size_t)kt * NT + slice * NTS + nt) * 64 + c];
  }
  __syncthreads();

  floatx4 acc[NTS];
#pragma unroll
  for (int nt = 0; nt < NTS; ++nt) acc[nt] = {0.f, 0.f, 0.f, 0.f};

#pragma unroll
  for (int kt = 0; kt < KT; ++kt) {
    int c0 = kt * 32 + kseg * 8;
    float4 xa = *(const float4*)(xr + c0);
    float4 xb = *(const float4*)(xr + c0 + 4);
    float hv[8] = {xa.x, xa.y, xa.z, xa.w, xb.x, xb.y, xb.z, xb.w};
    bf16x8 ah, al;
#pragma unroll
    for (int t = 0; t < 8; ++t) {
      __bf16 hb = (__bf16)hv[t];
      ah[t] = hb;
      al[t] = (__bf16)(hv[t] - (float)hb);
    }
#pragma unroll
    for (int nt = 0; nt < NTS; ++nt) {
      int base = (kt * NTS + nt) * 128 + lane;
      bf16x8 bh = __builtin_bit_cast(bf16x8, ((const ushort8_alias*)Bst)[base]);
      bf16x8 bl = __builtin_bit_cast(bf16x8, ((const ushort8_alias*)Bst)[base + 64]);
      acc[nt] = __builtin_amdgcn_mfma_f32_16x16x32_bf16(ah, bh, acc[nt], 0, 0, 0);
      acc[nt] = __builtin_amdgcn_mfma_f32_16x16x32_bf16(al, bh, acc[nt], 0, 0, 0);
      acc[nt] = __builtin_amdgcn_mfma_f32_16x16x32_bf16(ah, bl, acc[nt], 0, 0, 0);
    }
  }

#pragma unroll
  for (int nt = 0; nt < NTS; ++nt) {
    int n = slice * NCOL + nt * 16 + r;
    float* dst = (n < C) ? p : q;
    int col = (n < C) ? n : n - C;
#pragma unroll
    for (int gi = 0; gi < 4; ++gi) {
      int row = rowBase + kseg * 4 + gi;
      dst[(size_t)row * C + col] = acc[nt][gi];
    }
  }
}

// ---------------------------------------------------------------- BN1 stats (banked atomics)
template<int C>
__global__ __launch_bounds__(256) void edge_stats1v(const float* __restrict__ p,
                                                    const float* __restrict__ q,
                                                    const float* __restrict__ b1,
                                                    const int* __restrict__ idx,
                                                    float* __restrict__ statsL) {
  constexpr int G = C / 4;
  constexpr int KL = 64 / G;
  int tid = threadIdx.x, lane = tid & 63, wv = tid >> 6;
  int nd = blockIdx.x * 4 + wv;
  int b = nd >> 7;
  int g = lane % G, kl = lane / G;
  int bank = blockIdx.x & 7;

  __shared__ float sS[C], sSS[C];
  if (tid < C) { sS[tid] = 0.f; sSS[tid] = 0.f; }
  __syncthreads();

  const float* pr = p + (size_t)nd * C;
  float4 pv = *(const float4*)(pr + g * 4);
  float4 bv = *(const float4*)(b1 + g * 4);
  pv.x += bv.x; pv.y += bv.y; pv.z += bv.z; pv.w += bv.w;
  float4 s = {0, 0, 0, 0}, ss = {0, 0, 0, 0};
  const int* id = idx + (size_t)nd * KK;
#pragma unroll
  for (int k0 = 0; k0 < KK; k0 += KL) {
    int j = id[k0 + kl];
    float4 q4 = *(const float4*)(q + (size_t)(b * NN + j) * C + g * 4);
    float y;
    y = pv.x + q4.x; s.x += y; ss.x = fmaf(y, y, ss.x);
    y = pv.y + q4.y; s.y += y; ss.y = fmaf(y, y, ss.y);
    y = pv.z + q4.z; s.z += y; ss.z = fmaf(y, y, ss.z);
    y = pv.w + q4.w; s.w += y; ss.w = fmaf(y, y, ss.w);
  }
#pragma unroll
  for (int off = G; off < 64; off <<= 1) {
    s.x += __shfl_xor(s.x, off); ss.x += __shfl_xor(ss.x, off);
    s.y += __shfl_xor(s.y, off); ss.y += __shfl_xor(ss.y, off);
    s.z += __shfl_xor(s.z, off); ss.z += __shfl_xor(ss.z, off);
    s.w += __shfl_xor(s.w, off); ss.w += __shfl_xor(ss.w, off);
  }
  if (kl == 0) {
    atomicAdd(&sS[g * 4 + 0], s.x); atomicAdd(&sSS[g * 4 + 0], ss.x);
    atomicAdd(&sS[g * 4 + 1], s.y); atomicAdd(&sSS[g * 4 + 1], ss.y);
    atomicAdd(&sS[g * 4 + 2], s.z); atomicAdd(&sSS[g * 4 + 2], ss.z);
    atomicAdd(&sS[g * 4 + 3], s.w); atomicAdd(&sSS[g * 4 + 3], ss.w);
  }
  __syncthreads();
  if (tid < C) {
    atomicAdd(&statsL[bank * 256 + tid], sS[tid]);
    atomicAdd(&statsL[2048 + bank * 256 + tid], sSS[tid]);
  }
}

// ---------------------------------------------------------------- MFMA edge GEMM2 v13 (C=64 path, VGPR staging)
template<int C, int NCOL, int CK, int MPN>
__global__ __launch_bounds__(512, 4) void edge_gemm2_v13(
    const float* __restrict__ p, const float* __restrict__ q,
    const int* __restrict__ idx,
    const float* __restrict__ statsL,
    const float* __restrict__ g1, const float* __restrict__ e1,
    const float* __restrict__ b1,
    const u16* __restrict__ Wh, const u16* __restrict__ Wl,
    const float* __restrict__ b2,
    float* __restrict__ zmax, float* __restrict__ zmin,
    float* __restrict__ s2b, float* __restrict__ ss2b) {
  constexpr int KT = C / 32;
  constexpr int NT = C / 16;
  constexpr int NSLICE = C / NCOL;
  constexpr int NTS = NCOL / 16;
  constexpr int NWIN = KT / CK;
  constexpr int CCH = CK * NTS * 2 * 64;
  constexpr int NPB = 8 * MPN;       // nodes per block
  constexpr int GPB = NN / NPB;      // node-groups per batch
  __shared__ __align__(16) u16 Bst[CCH * 8];
  __shared__ float sScl[C], sShf[C];
  __shared__ float sS[NCOL], sSS[NCOL];

  int tid = threadIdx.x, lane = tid & 63, wv = tid >> 6;
  int r = lane & 15, kseg = lane >> 4;

  int g = blockIdx.x / NSLICE, slice = blockIdx.x % NSLICE;
  int u = g >> 3, xcd = g & 7;
  int b = xcd + 8 * (u / GPB);
  int nodeBase = b * NN + (u % GPB) * NPB;

  if (tid < C) {
    float s = 0.f, ssum = 0.f;
#pragma unroll
    for (int k = 0; k < 8; ++k) {
      s += statsL[k * 256 + tid];
      ssum += statsL[2048 + k * 256 + tid];
    }
    float mean = s / (float)MEDGE;
    float var = ssum / (float)MEDGE - mean * mean;
    if (var < 0.f) var = 0.f;
    float sc = g1[tid] * rsqrtf(var + 1e-5f);
    sScl[tid] = sc;
    sShf[tid] = e1[tid] - mean * sc + sc * b1[tid];
  }
  if (tid < NCOL) { sS[tid] = 0.f; sSS[tid] = 0.f; }

  int nd[MPN];
  const float *pr[MPN], *qr[MPN];
#pragma unroll
  for (int m = 0; m < MPN; ++m) {
    nd[m] = nodeBase + wv * MPN + m;
    int j = idx[(size_t)nd[m] * KK + r];
    pr[m] = p + (size_t)nd[m] * C;
    qr[m] = q + (size_t)(b * NN + j) * C;
  }

  floatx4 acc[MPN][NTS];
#pragma unroll
  for (int nt = 0; nt < NTS; ++nt) {
    float bv = b2[slice * NCOL + nt * 16 + r];
#pragma unroll
    for (int m = 0; m < MPN; ++m) acc[m][nt] = {bv, bv, bv, bv};
  }

#pragma unroll
  for (int w = 0; w < NWIN; ++w) {
    if (w > 0) __syncthreads();
    for (int i = tid; i < CCH; i += 512) {
      int c = i & 63, h = (i >> 6) & 1, rest = i >> 7;
      int nt = rest % NTS, kk = rest / NTS;
      const ushort8_alias* src = h ? (const ushort8_alias*)Wl : (const ushort8_alias*)Wh;
      ((ushort8_alias*)Bst)[i] = src[((size_t)(w * CK + kk) * NT + slice * NTS + nt) * 64 + c];
    }
    __syncthreads();

#pragma unroll
    for (int kk = 0; kk < CK; ++kk) {
      int c0 = (w * CK + kk) * 32 + kseg * 8;
      float4 sa = *(const float4*)(sScl + c0);
      float4 sb = *(const float4*)(sScl + c0 + 4);
      float4 ta = *(const float4*)(sShf + c0);
      float4 tb = *(const float4*)(sShf + c0 + 4);
      bf16x8 ah[MPN], al[MPN];
#pragma unroll
      for (int m = 0; m < MPN; ++m) {
        float4 pa = *(const float4*)(pr[m] + c0);
        float4 pb = *(const float4*)(pr[m] + c0 + 4);
        float4 qa = *(const float4*)(qr[m] + c0);
        float4 qb = *(const float4*)(qr[m] + c0 + 4);
        float hv[8];
        hv[0] = fmaxf(fmaf(pa.x + qa.x, sa.x, ta.x), 0.f);
        hv[1] = fmaxf(fmaf(pa.y + qa.y, sa.y, ta.y), 0.f);
        hv[2] = fmaxf(fmaf(pa.z + qa.z, sa.z, ta.z), 0.f);
        hv[3] = fmaxf(fmaf(pa.w + qa.w, sa.w, ta.w), 0.f);
        hv[4] = fmaxf(fmaf(pb.x + qb.x, sb.x, tb.x), 0.f);
        hv[5] = fmaxf(fmaf(pb.y + qb.y, sb.y, tb.y), 0.f);
        hv[6] = fmaxf(fmaf(pb.z + qb.z, sb.z, tb.z), 0.f);
        hv[7] = fmaxf(fmaf(pb.w + qb.w, sb.w, tb.w), 0.f);
#pragma unroll
        for (int t = 0; t < 8; ++t) {
          __bf16 hb = (__bf16)hv[t];
          ah[m][t] = hb;
          al[m][t] = (__bf16)(hv[t] - (float)hb);
        }
      }
#pragma unroll
      for (int nt = 0; nt < NTS; ++nt) {
        int base = (kk * NTS + nt) * 128 + lane;
        bf16x8 bh = __builtin_bit_cast(bf16x8, ((const ushort8_alias*)Bst)[base]);
        bf16x8 bl = __builtin_bit_cast(bf16x8, ((const ushort8_alias*)Bst)[base + 64]);
#pragma unroll
        for (int m = 0; m < MPN; ++m) {
          acc[m][nt] = __builtin_amdgcn_mfma_f32_16x16x32_bf16(ah[m], bh, acc[m][nt], 0, 0, 0);
          acc[m][nt] = __builtin_amdgcn_mfma_f32_16x16x32_bf16(al[m], bh, acc[m][nt], 0, 0, 0);
          acc[m][nt] = __builtin_amdgcn_mfma_f32_16x16x32_bf16(ah[m], bl, acc[m][nt], 0, 0, 0);
        }
      }
    }
  }

  int bank = blockIdx.x & 7;
#pragma unroll
  for (int m = 0; m < MPN; ++m) {
#pragma unroll
    for (int nt = 0; nt < NTS; ++nt) {
      float s = 0.f, ss = 0.f, mx = -INFINITY, mn = INFINITY;
#pragma unroll
      for (int gi = 0; gi < 4; ++gi) {
        float z = acc[m][nt][gi];
        s += z; ss = fmaf(z, z, ss);
        mx = fmaxf(mx, z); mn = fminf(mn, z);
      }
      mx = fmaxf(mx, __shfl_xor(mx, 16)); mn = fminf(mn, __shfl_xor(mn, 16));
      s += __shfl_xor(s, 16); ss += __shfl_xor(ss, 16);
      mx = fmaxf(mx, __shfl_xor(mx, 32)); mn = fminf(mn, __shfl_xor(mn, 32));
      s += __shfl_xor(s, 32); ss += __shfl_xor(ss, 32);
      if (kseg == 0) {
        int colL = nt * 16 + r;
        int col = slice * NCOL + colL;
        zmax[(size_t)nd[m] * C + col] = mx;
        zmin[(size_t)nd[m] * C + col] = mn;
        atomicAdd(&sS[colL], s);
        atomicAdd(&sSS[colL], ss);
      }
    }
  }
  __syncthreads();
  if (tid < NCOL) {
    atomicAdd(&s2b[bank * 256 + slice * NCOL + tid], sS[tid]);
    atomicAdd(&ss2b[bank * 256 + slice * NCOL + tid], sSS[tid]);
  }
}

// ---------------------------------------------------------------- MFMA edge GEMM2 v16 (persistent weights, barrier-free node loop)
// R3-R6 showed time ~= SUM of MFMA+VALU+LDS pipes: per-window staging barriers
// keep all waves in lockstep (all-VALU, then all-MFMA, then all-stall). v16:
// 16-wave (1024-thread) blocks stage the FULL-K weight slice into LDS once
// (C=256/NCOL=128: 128KB; C=128: 64KB), one barrier, then loop over ITER
// node-groups with ZERO barriers - Bst is read-only, outputs per-node, stats
// via LDS atomics. Waves desynchronize at memory stalls -> cross-wave pipe
// overlap; time should move from sum(pipes) toward max(pipes).
template<int C, int NCOL, int MPN, int BLKS>
__global__ __launch_bounds__(1024, 4) void edge_gemm2_v16(
    const float* __restrict__ p, const float* __restrict__ q,
    const int* __restrict__ idx,
    const float* __restrict__ statsL,
    const float* __restrict__ g1, const float* __restrict__ e1,
    const float* __restrict__ b1,
    const u16* __restrict__ Wh, const u16* __restrict__ Wl,
    const float* __restrict__ b2,
    float* __restrict__ zmax, float* __restrict__ zmin,
    float* __restrict__ s2b, float* __restrict__ ss2b) {
  constexpr int KT = C / 32;
  constexpr int NT = C / 16;
  constexpr int NSLICE = C / NCOL;
  constexpr int NTS = NCOL / 16;
  constexpr int CCH = KT * NTS * 2 * 64;       // ushort8 units, FULL K range
  constexpr int NPG = 16 * MPN;                // nodes per group (16 waves)
  constexpr int ITER = MNODE / NPG / BLKS;     // groups per block
  __shared__ __align__(16) u16 Bst[CCH * 8];
  __shared__ float sScl[C], sShf[C];
  __shared__ float sS[NCOL], sSS[NCOL];

  int tid = threadIdx.x, lane = tid & 63, wv = tid >> 6;   // wv in [0,16)
  int r = lane & 15, kseg = lane >> 4;
  int blk = blockIdx.x / NSLICE, slice = blockIdx.x % NSLICE;

  if (tid < C) {
    float s = 0.f, ssum = 0.f;
#pragma unroll
    for (int k = 0; k < 8; ++k) {
      s += statsL[k * 256 + tid];
      ssum += statsL[2048 + k * 256 + tid];
    }
    float mean = s / (float)MEDGE;
    float var = ssum / (float)MEDGE - mean * mean;
    if (var < 0.f) var = 0.f;
    float sc = g1[tid] * rsqrtf(var + 1e-5f);
    sScl[tid] = sc;
    sShf[tid] = e1[tid] - mean * sc + sc * b1[tid];
  }
  if (tid < NCOL) { sS[tid] = 0.f; sSS[tid] = 0.f; }

  // stage full-K weight slice once (VGPR staging, coalesced 16B per lane)
  for (int i = tid; i < CCH; i += 1024) {
    int c = i & 63, h = (i >> 6) & 1, rest = i >> 7;
    int nt = rest % NTS, kt = rest / NTS;
    const ushort8_alias* src = h ? (const ushort8_alias*)Wl : (const ushort8_alias*)Wh;
    ((ushort8_alias*)Bst)[i] = src[((size_t)kt * NT + slice * NTS + nt) * 64 + c];
  }
  __syncthreads();   // the ONLY barrier before the node loop

#pragma unroll 1
  for (int it = 0; it < ITER; ++it) {
    int group = blk * ITER + it;
    int nodeBase = group * NPG + wv * MPN;

    int nd[MPN];
    const float *pr[MPN], *qr[MPN];
#pragma unroll
    for (int m = 0; m < MPN; ++m) {
      nd[m] = nodeBase + m;
      int b = nd[m] >> 7;
      int j = idx[(size_t)nd[m] * KK + r];
      pr[m] = p + (size_t)nd[m] * C;
      qr[m] = q + (size_t)(b * NN + j) * C;
    }

    floatx4 acc[MPN][NTS];
#pragma unroll
    for (int nt = 0; nt < NTS; ++nt) {
      float bv = b2[slice * NCOL + nt * 16 + r];
#pragma unroll
      for (int m = 0; m < MPN; ++m) acc[m][nt] = {bv, bv, bv, bv};
    }

#pragma unroll
    for (int kk = 0; kk < KT; ++kk) {
      int c0 = kk * 32 + kseg * 8;
      float4 sa = *(const float4*)(sScl + c0);
      float4 sb = *(const float4*)(sScl + c0 + 4);
      float4 ta = *(const float4*)(sShf + c0);
      float4 tb = *(const float4*)(sShf + c0 + 4);
      bf16x8 ah[MPN], al[MPN];
#pragma unroll
      for (int m = 0; m < MPN; ++m) {
        float4 pa = *(const float4*)(pr[m] + c0);
        float4 pb = *(const float4*)(pr[m] + c0 + 4);
        float4 qa = *(const float4*)(qr[m] + c0);
        float4 qb = *(const float4*)(qr[m] + c0 + 4);
        float hv[8];
        hv[0] = fmaxf(fmaf(pa.x + qa.x, sa.x, ta.x), 0.f);
        hv[1] = fmaxf(fmaf(pa.y + qa.y, sa.y, ta.y), 0.f);
        hv[2] = fmaxf(fmaf(pa.z + qa.z, sa.z, ta.z), 0.f);
        hv[3] = fmaxf(fmaf(pa.w + qa.w, sa.w, ta.w), 0.f);
        hv[4] = fmaxf(fmaf(pb.x + qb.x, sb.x, tb.x), 0.f);
        hv[5] = fmaxf(fmaf(pb.y + qb.y, sb.y, tb.y), 0.f);
        hv[6] = fmaxf(fmaf(pb.z + qb.z, sb.z, tb.z), 0.f);
        hv[7] = fmaxf(fmaf(pb.w + qb.w, sb.w, tb.w), 0.f);
#pragma unroll
        for (int t = 0; t < 8; ++t) {
          __bf16 hb = (__bf16)hv[t];
          ah[m][t] = hb;
          al[m][t] = (__bf16)(hv[t] - (float)hb);
        }
      }
#pragma unroll
      for (int nt = 0; nt < NTS; ++nt) {
        int base = (kk * NTS + nt) * 128 + lane;
        bf16x8 bh = __builtin_bit_cast(bf16x8, ((const ushort8_alias*)Bst)[base]);
        bf16x8 bl = __builtin_bit_cast(bf16x8, ((const ushort8_alias*)Bst)[base + 64]);
#pragma unroll
        for (int m = 0; m < MPN; ++m) {
          acc[m][nt] = __builtin_amdgcn_mfma_f32_16x16x32_bf16(ah[m], bh, acc[m][nt], 0, 0, 0);
          acc[m][nt] = __builtin_amdgcn_mfma_f32_16x16x32_bf16(al[m], bh, acc[m][nt], 0, 0, 0);
          acc[m][nt] = __builtin_amdgcn_mfma_f32_16x16x32_bf16(ah[m], bl, acc[m][nt], 0, 0, 0);
        }
      }
    }

#pragma unroll
    for (int m = 0; m < MPN; ++m) {
#pragma unroll
      for (int nt = 0; nt < NTS; ++nt) {
        float s = 0.f, ss = 0.f, mx = -INFINITY, mn = INFINITY;
#pragma unroll
        for (int gi = 0; gi < 4; ++gi) {
          float z = acc[m][nt][gi];
          s += z; ss = fmaf(z, z, ss);
          mx = fmaxf(mx, z); mn = fminf(mn, z);
        }
        mx = fmaxf(mx, __shfl_xor(mx, 16)); mn = fminf(mn, __shfl_xor(mn, 16));
        s += __shfl_xor(s, 16); ss += __shfl_xor(ss, 16);
        mx = fmaxf(mx, __shfl_xor(mx, 32)); mn = fminf(mn, __shfl_xor(mn, 32));
        s += __shfl_xor(s, 32); ss += __shfl_xor(ss, 32);
        if (kseg == 0) {
          int colL = nt * 16 + r;
          int col = slice * NCOL + colL;
          zmax[(size_t)nd[m] * C + col] = mx;
          zmin[(size_t)nd[m] * C + col] = mn;
          atomicAdd(&sS[colL], s);
          atomicAdd(&sSS[colL], ss);
        }
      }
    }
  }

  __syncthreads();
  int bank = blockIdx.x & 7;
  if (tid < NCOL) {
    atomicAdd(&s2b[bank * 256 + slice * NCOL + tid], sS[tid]);
    atomicAdd(&ss2b[bank * 256 + slice * NCOL + tid], sSS[tid]);
  }
}

// ---------------------------------------------------------------- finalize (banked BN2 params)
__global__ __launch_bounds__(256) void finalize2_kernel(const float* __restrict__ zmax,
                                                        const float* __restrict__ zmin,
                                                        const float* __restrict__ s2b,
                                                        const float* __restrict__ ss2b,
                                                        const float* __restrict__ g2,
                                                        const float* __restrict__ e2,
                                                        float* __restrict__ out, int Cmask) {
  int t = blockIdx.x * 256 + threadIdx.x;
  int c = t & Cmask;
  float s = 0.f, ss = 0.f;
#pragma unroll
  for (int k = 0; k < 8; ++k) {
    s += s2b[k * 256 + c];
    ss += ss2b[k * 256 + c];
  }
  float mean = s / (float)MEDGE;
  float var = ss / (float)MEDGE - mean * mean;
  if (var < 0.f) var = 0.f;
  float scl = g2[c] * rsqrtf(var + 1e-5f);
  float shf = e2[c] - mean * scl;
  float v = (scl >= 0.f) ? zmax[t] : zmin[t];
  out[t] = fmaxf(fmaf(v, scl, shf), 0.f);
}

// ---------------------------------------------------------------- fused L3 finalize + pool
__global__ __launch_bounds__(256) void fin3_pool(const float* __restrict__ zmax,
                                                 const float* __restrict__ zmin,
                                                 const float* __restrict__ s2b,
                                                 const float* __restrict__ ss2b,
                                                 const float* __restrict__ g2,
                                                 const float* __restrict__ e2,
                                                 float* __restrict__ pooled) {
  int b = blockIdx.x >> 2, cc = blockIdx.x & 3;
  int tid = threadIdx.x;
  int cl = tid & 63, ng = tid >> 6;       // 4 node-groups x 32 nodes
  int c = cc * 64 + cl;
  float s = 0.f, ss = 0.f;
#pragma unroll
  for (int k = 0; k < 8; ++k) { s += s2b[k * 256 + c]; ss += ss2b[k * 256 + c]; }
  float mean = s / (float)MEDGE;
  float var = ss / (float)MEDGE - mean * mean;
  if (var < 0.f) var = 0.f;
  float scl = g2[c] * rsqrtf(var + 1e-5f);
  float shf = e2[c] - mean * scl;

  float acc = 0.f, mx = -INFINITY;
  for (int n = ng * 32; n < ng * 32 + 32; ++n) {
    size_t t = (size_t)(b * NN + n) * 256 + c;
    float vx = zmax[t], vn = zmin[t];
    float v = (scl >= 0.f) ? vx : vn;
    float h = fmaxf(fmaf(v, scl, shf), 0.f);
    acc += h; mx = fmaxf(mx, h);
  }
  __shared__ float sSum[4][64], sMax[4][64];
  sSum[ng][cl] = acc; sMax[ng][cl] = mx;
  __syncthreads();
  if (ng == 0) {
    float a = sSum[0][cl] + sSum[1][cl] + sSum[2][cl] + sSum[3][cl];
    float m = fmaxf(fmaxf(sMax[0][cl], sMax[1][cl]), fmaxf(sMax[2][cl], sMax[3][cl]));
    pooled[b * 512 + c] = a * (1.f / 128.f);
    pooled[b * 512 + 256 + c] = m;
  }
}

// ---------------------------------------------------------------- FC tail
__global__ __launch_bounds__(256) void fc1_fused(const float* __restrict__ pooled,
                                                 const float* __restrict__ W,
                                                 const float* __restrict__ bias,
                                                 float* __restrict__ t1raw,
                                                 float* __restrict__ fs, float* __restrict__ fss) {
  int b = blockIdx.x, c = threadIdx.x;
  __shared__ float row[512];
  row[c] = pooled[b * 512 + c];
  row[c + 256] = pooled[b * 512 + 256 + c];
  __syncthreads();
  float acc = bias[c];
  for (int i = 0; i < 512; ++i) acc = fmaf(row[i], W[i * 256 + c], acc);
  t1raw[b * 256 + c] = acc;
  atomicAdd(&fs[c], acc);
  atomicAdd(&fss[c], acc * acc);
}

__global__ __launch_bounds__(256) void fc2_fused(const float* __restrict__ t1raw,
                                                 const float* __restrict__ fs,
                                                 const float* __restrict__ fss,
                                                 const float* __restrict__ g1,
                                                 const float* __restrict__ e1,
                                                 const float* __restrict__ W,
                                                 const float* __restrict__ bias,
                                                 float* __restrict__ t2raw,
                                                 float* __restrict__ gs, float* __restrict__ gss) {
  int b = blockIdx.x, c = threadIdx.x;
  __shared__ float row[256];
  {
    float mean = fs[c] / 128.f;
    float var = fss[c] / 128.f - mean * mean;
    if (var < 0.f) var = 0.f;
    float scl = g1[c] * rsqrtf(var + 1e-5f);
    float shf = e1[c] - mean * scl;
    row[c] = fmaxf(fmaf(t1raw[b * 256 + c], scl, shf), 0.f);
  }
  __syncthreads();
  if (c < 128) {
    float acc = bias[c];
    for (int i = 0; i < 256; ++i) acc = fmaf(row[i], W[i * 128 + c], acc);
    t2raw[b * 128 + c] = acc;
    atomicAdd(&gs[c], acc);
    atomicAdd(&gss[c], acc * acc);
  }
}

__global__ __launch_bounds__(256) void fc3_fused(const float* __restrict__ t2raw,
                                                 const float* __restrict__ gs,
                                                 const float* __restrict__ gss,
                                                 const float* __restrict__ g2,
                                                 const float* __restrict__ e2,
                                                 const float* __restrict__ W,
                                                 const float* __restrict__ bias,
                                                 float* __restrict__ out) {
  __shared__ float row[128 * 2];
  int t = threadIdx.x;
  if (t < 128) {
    float mean = gs[t] / 128.f;
    float var = gss[t] / 128.f - mean * mean;
    if (var < 0.f) var = 0.f;
    float scl = g2[t] * rsqrtf(var + 1e-5f);
    row[t] = scl;
    row[128 + t] = e2[t] - mean * scl;
  }
  __syncthreads();
  int b = t >> 1, jj = t & 1;
  float acc = bias[jj];
  for (int r = 0; r < 128; ++r) {
    float v = fmaxf(fmaf(t2raw[b * 128 + r], row[r], row[128 + r]), 0.f);
    acc = fmaf(v, W[r * 2 + jj], acc);
  }
  out[t] = acc;
}

// ---------------------------------------------------------------- per-layer driver

struct LayerPtrs {
  int* idx; float *p, *q, *zmx, *zmn;
};

template<int Cin, int C, bool DOFIN>
static void run_edgeconv(const float* xin,
                         const float* W1, const float* b1, const float* g1, const float* e1,
                         const float* b2, const float* g2, const float* e2,
                         const u16* Wh1, const u16* Wl1, const u16* Wh2, const u16* Wl2,
                         float* hout, float* statsL, const LayerPtrs& L, hipStream_t stream) {
  float* s2b = statsL + 4096;
  float* ss2b = statsL + 6144;

  knn_fused<Cin><<<dim3(BB * 2), dim3(256), 0, stream>>>(xin, L.idx);
  if constexpr (Cin >= 16) {
    constexpr int NSL1 = (2 * C) / 64;
    node_gemm_v2<Cin, 2 * C><<<dim3((MNODE / 128) * NSL1), dim3(512), 0, stream>>>(
        xin, Wh1, Wl1, L.p, L.q);
  } else {
    node_gemm<<<dim3(MNODE / 8), dim3(C), 0, stream>>>(xin, W1, L.p, L.q, Cin, C);
  }
  edge_stats1v<C><<<dim3(MNODE / 4), dim3(256), 0, stream>>>(L.p, L.q, b1, L.idx, statsL);
  if constexpr (C == 64) {
    // small layer: keep proven v13 (single window, stages 16KB once)
    edge_gemm2_v13<64, 64, 2, 2><<<dim3(MNODE / 16), dim3(512), 0, stream>>>(
        L.p, L.q, L.idx, statsL, g1, e1, b1, Wh2, Wl2, b2, L.zmx, L.zmn, s2b, ss2b);
  } else {
    // v16: persistent full-K weights, barrier-free node loop.
    //   C=128: NCOL=128, NSLICE=1, Bst 64KB,  BLKS=256 -> grid 256, ITER=2
    //   C=256: NCOL=128, NSLICE=2, Bst 128KB, BLKS=128 -> grid 256, ITER=4
    constexpr int NCOL = 128;
    constexpr int MPN = 2;
    constexpr int BLKS = (C == 256) ? 128 : 256;
    constexpr int NSL = C / NCOL;
    edge_gemm2_v16<C, NCOL, MPN, BLKS><<<dim3(NSL * BLKS), dim3(1024), 0, stream>>>(
        L.p, L.q, L.idx, statsL, g1, e1, b1, Wh2, Wl2, b2, L.zmx, L.zmn, s2b, ss2b);
  }
  if constexpr (DOFIN) {
    finalize2_kernel<<<dim3(MNODE * C / 256), dim3(256), 0, stream>>>(
        L.zmx, L.zmn, s2b, ss2b, g2, e2, hout, C - 1);
  }
}

// ---------------------------------------------------------------- launch

extern "C" void kernel_launch(void* const* d_in, const int* in_sizes, int n_in,
                              void* d_out, int out_size, void* d_ws, size_t ws_size,
                              hipStream_t stream) {
  const float* x   = (const float*)d_in[0];
  const float* w11 = (const float*)d_in[1];
  const float* b11 = (const float*)d_in[2];
  const float* g11 = (const float*)d_in[3];
  const float* e11 = (const float*)d_in[4];
  const float* w12 = (const float*)d_in[5];
  const float* b12 = (const float*)d_in[6];
  const float* g12 = (const float*)d_in[7];
  const float* e12 = (const float*)d_in[8];
  const float* w21 = (const float*)d_in[9];
  const float* b21 = (const float*)d_in[10];
  const float* g21 = (const float*)d_in[11];
  const float* e21 = (const float*)d_in[12];
  const float* w22 = (const float*)d_in[13];
  const float* b22 = (const float*)d_in[14];
  const float* g22 = (const float*)d_in[15];
  const float* e22 = (const float*)d_in[16];
  const float* w31 = (const float*)d_in[17];
  const float* b31 = (const float*)d_in[18];
  const float* g31 = (const float*)d_in[19];
  const float* e31 = (const float*)d_in[20];
  const float* w32 = (const float*)d_in[21];
  const float* b32 = (const float*)d_in[22];
  const float* g32 = (const float*)d_in[23];
  const float* e32 = (const float*)d_in[24];
  const float* fw1 = (const float*)d_in[25];
  const float* fb1 = (const float*)d_in[26];
  const float* fg1 = (const float*)d_in[27];
  const float* fe1 = (const float*)d_in[28];
  const float* fw2 = (const float*)d_in[29];
  const float* fb2 = (const float*)d_in[30];
  const float* fg2 = (const float*)d_in[31];
  const float* fe2 = (const float*)d_in[32];
  const float* fw3 = (const float*)d_in[33];
  const float* fb3 = (const float*)d_in[34];

  char* wsb = (char*)d_ws;
  size_t o = 0;
  auto alloc = [&](size_t bytes) -> void* {
    void* r = wsb + o;
    o += (bytes + 255) & ~(size_t)255;
    return r;
  };
  LayerPtrs L;
  L.idx   = (int*)  alloc((size_t)MNODE * KK * sizeof(int));
  L.p     = (float*)alloc((size_t)MNODE * 256 * sizeof(float));
  L.q     = (float*)alloc((size_t)MNODE * 256 * sizeof(float));
  L.zmx   = (float*)alloc((size_t)MNODE * 256 * sizeof(float));
  L.zmn   = (float*)alloc((size_t)MNODE * 256 * sizeof(float));
  // per-layer packed weights (filled once by pack_all)
  u16* h12 = (u16*)alloc(64 * 64 * sizeof(u16));
  u16* l12 = (u16*)alloc(64 * 64 * sizeof(u16));
  u16* h22 = (u16*)alloc(128 * 128 * sizeof(u16));
  u16* l22 = (u16*)alloc(128 * 128 * sizeof(u16));
  u16* h32 = (u16*)alloc(256 * 256 * sizeof(u16));
  u16* l32 = (u16*)alloc(256 * 256 * sizeof(u16));
  u16* h21 = (u16*)alloc(64 * 256 * sizeof(u16));
  u16* l21 = (u16*)alloc(64 * 256 * sizeof(u16));
  u16* h31 = (u16*)alloc(128 * 512 * sizeof(u16));
  u16* l31 = (u16*)alloc(128 * 512 * sizeof(u16));
  float* statsAll = (float*)alloc((3 * 8192 + 1024) * sizeof(float));
  float* h1buf   = (float*)alloc((size_t)MNODE * 64 * sizeof(float));
  float* h2buf   = (float*)alloc((size_t)MNODE * 128 * sizeof(float));
  float* pooled  = (float*)alloc(128 * 512 * sizeof(float));
  float* t1raw   = (float*)alloc(128 * 256 * sizeof(float));
  float* t2raw   = (float*)alloc(128 * 128 * sizeof(float));

  float* fcstats = statsAll + 3 * 8192;
  float* fs  = fcstats;
  float* fss = fcstats + 256;
  float* gs  = fcstats + 512;
  float* gss = fcstats + 768;

  (void)hipMemsetAsync(statsAll, 0, (3 * 8192 + 1024) * sizeof(float), stream);
  pack_all<<<dim3(656), dim3(256), 0, stream>>>(w12, w22, w32, w21, w31,
      h12, l12, h22, l22, h32, l32, h21, l21, h31, l31);

  run_edgeconv<6, 64, true>(x, w11, b11, g11, e11, b12, g12, e12,
                            nullptr, nullptr, h12, l12,
                            h1buf, statsAll, L, stream);
  run_edgeconv<64, 128, true>(h1buf, nullptr, b21, g21, e21, b22, g22, e22,
                              h21, l21, h22, l22,
                              h2buf, statsAll + 8192, L, stream);
  run_edgeconv<128, 256, false>(h2buf, nullptr, b31, g31, e31, b32, g32, e32,
                                h31, l31, h32, l32,
                                nullptr, statsAll + 16384, L, stream);

  // fused finalize(L3) + pool, straight into pooled (h3 never materialized)
  {
    float* s2b3 = statsAll + 16384 + 4096;
    float* ss2b3 = statsAll + 16384 + 6144;
    fin3_pool<<<dim3(BB * 4), dim3(256), 0, stream>>>(L.zmx, L.zmn, s2b3, ss2b3,
                                                      g32, e32, pooled);
  }
  fc1_fused<<<dim3(BB), dim3(256), 0, stream>>>(pooled, fw1, fb1, t1raw, fs, fss);
  fc2_fused<<<dim3(BB), dim3(256), 0, stream>>>(t1raw, fs, fss, fg1, fe1, fw2, fb2, t2raw, gs, gss);
  fc3_fused<<<dim3(1), dim3(256), 0, stream>>>(t2raw, gs, gss, fg2, fe2, fw3, fb3, (float*)d_out);
}

// Round 8
// 622.456 us; speedup vs baseline: 3.2760x; 3.2760x over previous
//
#include <hip/hip_runtime.h>
#include <math.h>

#define BB 128
#define NN 128
#define KK 16
#define MEDGE (BB*NN*KK)   // 262144 edges
#define MNODE (BB*NN)      // 16384 nodes

typedef __bf16 bf16x8 __attribute__((ext_vector_type(8)));
typedef float  floatx4 __attribute__((ext_vector_type(4)));
typedef unsigned short u16;
typedef u16 ushort8_alias __attribute__((ext_vector_type(8)));

// ---------------------------------------------------------------- utilities

__device__ __forceinline__ unsigned ord32(float f) {
  unsigned u = __float_as_uint(f);
  return (u & 0x80000000u) ? ~u : (u | 0x80000000u);
}

__device__ __forceinline__ u16 bf16_rne_bits(float x) {
  unsigned u = __float_as_uint(x);
  return (u16)((u + 0x7FFF + ((u >> 16) & 1)) >> 16);
}

// ---------------------------------------------------------------- fused kNN (dist + ballot-radix select)
template<int C>
__global__ __launch_bounds__(256) void knn_fused(const float* __restrict__ x,
                                                 int* __restrict__ idx) {
  constexpr int S = C + 2;
  constexpr int DS = NN + 2;
  constexpr int XSZ = (NN * S > 64 * DS) ? NN * S : 64 * DS;   // union sizing
  __shared__ float xs[XSZ];   // x staging, then reused as Dl[64 * DS]
  __shared__ float sq[NN];
  int b = blockIdx.x >> 1, half = blockIdx.x & 1;
  const float* xb = x + (size_t)b * NN * C;
  int tid = threadIdx.x;

  for (int t = tid; t < NN * C; t += 256) {
    int row = t / C, c = t - row * C;
    xs[row * S + c] = xb[t];
  }
  __syncthreads();
  if (tid < NN) {
    const float* xr = xs + tid * S;
    float s = 0.f;
    for (int c = 0; c < C; ++c) s = fmaf(xr[c], xr[c], s);
    sq[tid] = s;
  }
  __syncthreads();

  // dist: 64 rows x 128 cols; thread = 8 rows x 4 cols (in registers)
  int rg = tid >> 5, cg = tid & 31;
  int r0 = half * 64 + rg * 8;
  float acc[8][4];
#pragma unroll
  for (int i = 0; i < 8; ++i)
#pragma unroll
    for (int j = 0; j < 4; ++j) acc[i][j] = 0.f;
  for (int c = 0; c < C; c += 2) {
    float2 av[8], bv[4];
#pragma unroll
    for (int i = 0; i < 8; ++i) av[i] = *(const float2*)&xs[(r0 + i) * S + c];
#pragma unroll
    for (int j = 0; j < 4; ++j) bv[j] = *(const float2*)&xs[(cg + 32 * j) * S + c];
#pragma unroll
    for (int i = 0; i < 8; ++i)
#pragma unroll
      for (int j = 0; j < 4; ++j) {
        acc[i][j] = fmaf(av[i].x, bv[j].x, acc[i][j]);
        acc[i][j] = fmaf(av[i].y, bv[j].y, acc[i][j]);
      }
  }
  float dv[8][4];
#pragma unroll
  for (int i = 0; i < 8; ++i) {
    float sn = sq[r0 + i];
#pragma unroll
    for (int j = 0; j < 4; ++j) dv[i][j] = sn - 2.f * acc[i][j] + sq[cg + 32 * j];
  }
  __syncthreads();  // all reads of xs complete
  float* Dl = xs;
#pragma unroll
  for (int i = 0; i < 8; ++i)
#pragma unroll
    for (int j = 0; j < 4; ++j)
      Dl[(rg * 8 + i) * DS + (cg + 32 * j)] = dv[i][j];
  __syncthreads();

  int lane = tid & 63, wv = tid >> 6;
  unsigned long long lmaskLT = (1ull << lane) - 1ull;   // bits below my lane
  for (int t = 0; t < 16; ++t) {
    int lr = wv * 16 + t;
    int nd = b * NN + half * 64 + lr;
    unsigned k0 = ord32(Dl[lr * DS + lane]);
    unsigned k1 = ord32(Dl[lr * DS + lane + 64]);
    int* out = idx + (size_t)nd * KK;

    // radix search: find the (32-bd)-bit prefix of the 16th-smallest key
    unsigned prefix = 0;
    int remaining = KK;      // how many still to take inside current group
    int G = 2 * 64;          // current prefix-group size
    int bd = 32;
    while (bd > 0) {
      --bd;
      unsigned pp = prefix << 1;
      bool m0 = (k0 >> bd) == pp;
      bool m1 = (k1 >> bd) == pp;
      int cnt0 = __popcll(__ballot(m0)) + __popcll(__ballot(m1));
      if (remaining <= cnt0) { prefix = pp; G = cnt0; }
      else                   { remaining -= cnt0; prefix = pp | 1; G -= cnt0; }
      if (G == remaining) break;   // whole group selected; low bits irrelevant
    }

    // emit: all keys strictly below the group + lowest-index `remaining` ties
    bool lt0 = (k0 >> bd) < prefix, eq0 = (k0 >> bd) == prefix;
    bool lt1 = (k1 >> bd) < prefix, eq1 = (k1 >> bd) == prefix;
    unsigned long long e0 = __ballot(eq0), e1 = __ballot(eq1);
    int c0 = __popcll(e0);
    int r0t = __popcll(e0 & lmaskLT);
    int r1t = c0 + __popcll(e1 & lmaskLT);
    bool s0 = lt0 || (eq0 && (r0t < remaining));
    bool s1 = lt1 || (eq1 && (r1t < remaining));
    unsigned long long S0 = __ballot(s0), S1 = __ballot(s1);
    int pos0 = __popcll(S0 & lmaskLT);
    int pos1 = __popcll(S0) + __popcll(S1 & lmaskLT);
    if (s0) out[pos0] = lane;
    if (s1) out[pos1] = lane + 64;
  }
}

// ---------------------------------------------------------------- node GEMM (scalar, layer-1 only)
__global__ __launch_bounds__(256) void node_gemm(const float* __restrict__ x,
                                                 const float* __restrict__ W,
                                                 float* __restrict__ p, float* __restrict__ q,
                                                 int Cin, int Cout) {
  int c = threadIdx.x;
  __shared__ float xr[128];
  for (int r = 0; r < 8; ++r) {
    int row = blockIdx.x * 8 + r;
    __syncthreads();
    for (int i = c; i < Cin; i += blockDim.x) xr[i] = x[(size_t)row * Cin + i];
    __syncthreads();
    float a = 0.f, qv = 0.f;
    for (int i = 0; i < Cin; ++i) {
      float xv = xr[i];
      a  = fmaf(xv, W[i * Cout + c], a);
      qv = fmaf(xv, W[(Cin + i) * Cout + c], qv);
    }
    p[(size_t)row * Cout + c] = a - qv;
    q[(size_t)row * Cout + c] = qv;
  }
}

// ---------------------------------------------------------------- weight packing (device bodies)
template<int K, int N>
__device__ __forceinline__ void pack1_body(const float* __restrict__ W1,
                                           u16* __restrict__ Wh, u16* __restrict__ Wl,
                                           int blk, int tidx) {
  int t = blk * 256 + tidx;
  if (t >= K * N) return;
  constexpr int C = N / 2;
  constexpr int NT = N / 16;
  int j = t & 7, lane = (t >> 3) & 63, tile = t >> 9;
  int nt = tile % NT, kt = tile / NT;
  int row = kt * 32 + (lane >> 4) * 8 + j;
  int col = nt * 16 + (lane & 15);
  float w;
  if (col < C) w = W1[row * C + col] - W1[(K + row) * C + col];
  else         w = W1[(K + row) * C + (col - C)];
  u16 h = bf16_rne_bits(w);
  float hf = __uint_as_float(((unsigned)h) << 16);
  Wh[t] = h;
  Wl[t] = bf16_rne_bits(w - hf);
}

template<int C>
__device__ __forceinline__ void pack2_body(const float* __restrict__ W,
                                           u16* __restrict__ Wh, u16* __restrict__ Wl,
                                           int blk, int tidx) {
  int t = blk * 256 + tidx;
  if (t >= C * C) return;
  constexpr int NT = C / 16;
  int j = t & 7, lane = (t >> 3) & 63, tile = t >> 9;
  int nt = tile % NT, kt = tile / NT;
  int row = kt * 32 + (lane >> 4) * 8 + j;
  int col = nt * 16 + (lane & 15);
  float w = W[row * C + col];
  u16 h = bf16_rne_bits(w);
  float hf = __uint_as_float(((unsigned)h) << 16);
  Wh[t] = h;
  Wl[t] = bf16_rne_bits(w - hf);
}

// one dispatch packs all 5 weight matrices into per-layer buffers
__global__ __launch_bounds__(256) void pack_all(
    const float* __restrict__ w12, const float* __restrict__ w22, const float* __restrict__ w32,
    const float* __restrict__ w21, const float* __restrict__ w31,
    u16* h12, u16* l12, u16* h22, u16* l22, u16* h32, u16* l32,
    u16* h21, u16* l21, u16* h31, u16* l31) {
  int blk = blockIdx.x, tidx = threadIdx.x;
  if (blk < 16)        pack2_body<64 >(w12, h12, l12, blk,        tidx);
  else if (blk < 80)   pack2_body<128>(w22, h22, l22, blk - 16,   tidx);
  else if (blk < 336)  pack2_body<256>(w32, h32, l32, blk - 80,   tidx);
  else if (blk < 400)  pack1_body<64, 256>(w21, h21, l21, blk - 336, tidx);
  else                 pack1_body<128, 512>(w31, h31, l31, blk - 400, tidx);
}

// ---------------------------------------------------------------- node GEMM v2 (v9-style)
template<int K, int N>
__global__ __launch_bounds__(512, 4) void node_gemm_v2(
    const float* __restrict__ x, const u16* __restrict__ Wh, const u16* __restrict__ Wl,
    float* __restrict__ p, float* __restrict__ q) {
  constexpr int C = N / 2;
  constexpr int KT = K / 32;
  constexpr int NT = N / 16;
  constexpr int NCOL = 64, NTS = 4;
  constexpr int NSLICE = N / 64;
  constexpr int CCH = KT * NTS * 2 * 64;
  __shared__ __align__(16) u16 Bst[CCH * 8];

  int tid = threadIdx.x, lane = tid & 63, wv = tid >> 6;
  int r = lane & 15, kseg = lane >> 4;
  int g = blockIdx.x / NSLICE, slice = blockIdx.x % NSLICE;
  int rowBase = g * 128 + wv * 16;
  const float* xr = x + (size_t)(rowBase + r) * K;

  for (int i = tid; i < CCH; i += 512) {
    int c = i & 63, h = (i >> 6) & 1, rest = i >> 7;
    int nt = rest % NTS, kt = rest / NTS;
    const ushort8_alias* src = h ? (const ushort8_alias*)Wl : (const ushort8_alias*)Wh;
    ((ushort8_alias*)Bst)[i] = src[((size_t)kt * NT + slice * NTS + nt) * 64 + c];
  }
  __syncthreads();

  floatx4 acc[NTS];
#pragma unroll
  for (int nt = 0; nt < NTS; ++nt) acc[nt] = {0.f, 0.f, 0.f, 0.f};

#pragma unroll
  for (int kt = 0; kt < KT; ++kt) {
    int c0 = kt * 32 + kseg * 8;
    float4 xa = *(const float4*)(xr + c0);
    float4 xb = *(const float4*)(xr + c0 + 4);
    float hv[8] = {xa.x, xa.y, xa.z, xa.w, xb.x, xb.y, xb.z, xb.w};
    bf16x8 ah, al;
#pragma unroll
    for (int t = 0; t < 8; ++t) {
      __bf16 hb = (__bf16)hv[t];
      ah[t] = hb;
      al[t] = (__bf16)(hv[t] - (float)hb);
    }
#pragma unroll
    for (int nt = 0; nt < NTS; ++nt) {
      int base = (kt * NTS + nt) * 128 + lane;
      bf16x8 bh = __builtin_bit_cast(bf16x8, ((const ushort8_alias*)Bst)[base]);
      bf16x8 bl = __builtin_bit_cast(bf16x8, ((const ushort8_alias*)Bst)[base + 64]);
      acc[nt] = __builtin_amdgcn_mfma_f32_16x16x32_bf16(ah, bh, acc[nt], 0, 0, 0);
      acc[nt] = __builtin_amdgcn_mfma_f32_16x16x32_bf16(al, bh, acc[nt], 0, 0, 0);
      acc[nt] = __builtin_amdgcn_mfma_f32_16x16x32_bf16(ah, bl, acc[nt], 0, 0, 0);
    }
  }

#pragma unroll
  for (int nt = 0; nt < NTS; ++nt) {
    int n = slice * NCOL + nt * 16 + r;
    float* dst = (n < C) ? p : q;
    int col = (n < C) ? n : n - C;
#pragma unroll
    for (int gi = 0; gi < 4; ++gi) {
      int row = rowBase + kseg * 4 + gi;
      dst[(size_t)row * C + col] = acc[nt][gi];
    }
  }
}

// ---------------------------------------------------------------- BN1 stats (banked atomics)
template<int C>
__global__ __launch_bounds__(256) void edge_stats1v(const float* __restrict__ p,
                                                    const float* __restrict__ q,
                                                    const float* __restrict__ b1,
                                                    const int* __restrict__ idx,
                                                    float* __restrict__ statsL) {
  constexpr int G = C / 4;
  constexpr int KL = 64 / G;
  int tid = threadIdx.x, lane = tid & 63, wv = tid >> 6;
  int nd = blockIdx.x * 4 + wv;
  int b = nd >> 7;
  int g = lane % G, kl = lane / G;
  int bank = blockIdx.x & 7;

  __shared__ float sS[C], sSS[C];
  if (tid < C) { sS[tid] = 0.f; sSS[tid] = 0.f; }
  __syncthreads();

  const float* pr = p + (size_t)nd * C;
  float4 pv = *(const float4*)(pr + g * 4);
  float4 bv = *(const float4*)(b1 + g * 4);
  pv.x += bv.x; pv.y += bv.y; pv.z += bv.z; pv.w += bv.w;
  float4 s = {0, 0, 0, 0}, ss = {0, 0, 0, 0};
  const int* id = idx + (size_t)nd * KK;
#pragma unroll
  for (int k0 = 0; k0 < KK; k0 += KL) {
    int j = id[k0 + kl];
    float4 q4 = *(const float4*)(q + (size_t)(b * NN + j) * C + g * 4);
    float y;
    y = pv.x + q4.x; s.x += y; ss.x = fmaf(y, y, ss.x);
    y = pv.y + q4.y; s.y += y; ss.y = fmaf(y, y, ss.y);
    y = pv.z + q4.z; s.z += y; ss.z = fmaf(y, y, ss.z);
    y = pv.w + q4.w; s.w += y; ss.w = fmaf(y, y, ss.w);
  }
#pragma unroll
  for (int off = G; off < 64; off <<= 1) {
    s.x += __shfl_xor(s.x, off); ss.x += __shfl_xor(ss.x, off);
    s.y += __shfl_xor(s.y, off); ss.y += __shfl_xor(ss.y, off);
    s.z += __shfl_xor(s.z, off); ss.z += __shfl_xor(ss.z, off);
    s.w += __shfl_xor(s.w, off); ss.w += __shfl_xor(ss.w, off);
  }
  if (kl == 0) {
    atomicAdd(&sS[g * 4 + 0], s.x); atomicAdd(&sSS[g * 4 + 0], ss.x);
    atomicAdd(&sS[g * 4 + 1], s.y); atomicAdd(&sSS[g * 4 + 1], ss.y);
    atomicAdd(&sS[g * 4 + 2], s.z); atomicAdd(&sSS[g * 4 + 2], ss.z);
    atomicAdd(&sS[g * 4 + 3], s.w); atomicAdd(&sSS[g * 4 + 3], ss.w);
  }
  __syncthreads();
  if (tid < C) {
    atomicAdd(&statsL[bank * 256 + tid], sS[tid]);
    atomicAdd(&statsL[2048 + bank * 256 + tid], sSS[tid]);
  }
}

// ---------------------------------------------------------------- MFMA edge GEMM2 v17
// = R4's v13 (best verified: MPN=2 node blocking, acc=64 AGPR, VGPR staging)
// + single-z output: sign(scl2)=sign(g2[c]) is known at launch (rsqrt>0), so
// the kernel selects mx/mn by g2 at write time and emits ONE buffer --
// halves z write traffic here and z read traffic in finalize/pool.
template<int C, int NCOL, int CK, int MPN>
__global__ __launch_bounds__(512, 4) void edge_gemm2_v17(
    const float* __restrict__ p, const float* __restrict__ q,
    const int* __restrict__ idx,
    const float* __restrict__ statsL,
    const float* __restrict__ g1, const float* __restrict__ e1,
    const float* __restrict__ b1,
    const u16* __restrict__ Wh, const u16* __restrict__ Wl,
    const float* __restrict__ b2, const float* __restrict__ g2,
    float* __restrict__ z,
    float* __restrict__ s2b, float* __restrict__ ss2b) {
  constexpr int KT = C / 32;
  constexpr int NT = C / 16;
  constexpr int NSLICE = C / NCOL;
  constexpr int NTS = NCOL / 16;
  constexpr int NWIN = KT / CK;
  constexpr int CCH = CK * NTS * 2 * 64;
  constexpr int NPB = 8 * MPN;       // nodes per block
  constexpr int GPB = NN / NPB;      // node-groups per batch
  __shared__ __align__(16) u16 Bst[CCH * 8];
  __shared__ float sScl[C], sShf[C];
  __shared__ float sS[NCOL], sSS[NCOL];

  int tid = threadIdx.x, lane = tid & 63, wv = tid >> 6;
  int r = lane & 15, kseg = lane >> 4;

  int g = blockIdx.x / NSLICE, slice = blockIdx.x % NSLICE;
  int u = g >> 3, xcd = g & 7;
  int b = xcd + 8 * (u / GPB);
  int nodeBase = b * NN + (u % GPB) * NPB;

  if (tid < C) {
    float s = 0.f, ssum = 0.f;
#pragma unroll
    for (int k = 0; k < 8; ++k) {
      s += statsL[k * 256 + tid];
      ssum += statsL[2048 + k * 256 + tid];
    }
    float mean = s / (float)MEDGE;
    float var = ssum / (float)MEDGE - mean * mean;
    if (var < 0.f) var = 0.f;
    float sc = g1[tid] * rsqrtf(var + 1e-5f);
    sScl[tid] = sc;
    sShf[tid] = e1[tid] - mean * sc + sc * b1[tid];
  }
  if (tid < NCOL) { sS[tid] = 0.f; sSS[tid] = 0.f; }

  int nd[MPN];
  const float *pr[MPN], *qr[MPN];
#pragma unroll
  for (int m = 0; m < MPN; ++m) {
    nd[m] = nodeBase + wv * MPN + m;
    int j = idx[(size_t)nd[m] * KK + r];
    pr[m] = p + (size_t)nd[m] * C;
    qr[m] = q + (size_t)(b * NN + j) * C;
  }

  floatx4 acc[MPN][NTS];
#pragma unroll
  for (int nt = 0; nt < NTS; ++nt) {
    float bv = b2[slice * NCOL + nt * 16 + r];
#pragma unroll
    for (int m = 0; m < MPN; ++m) acc[m][nt] = {bv, bv, bv, bv};
  }

#pragma unroll
  for (int w = 0; w < NWIN; ++w) {
    if (w > 0) __syncthreads();
    for (int i = tid; i < CCH; i += 512) {
      int c = i & 63, h = (i >> 6) & 1, rest = i >> 7;
      int nt = rest % NTS, kk = rest / NTS;
      const ushort8_alias* src = h ? (const ushort8_alias*)Wl : (const ushort8_alias*)Wh;
      ((ushort8_alias*)Bst)[i] = src[((size_t)(w * CK + kk) * NT + slice * NTS + nt) * 64 + c];
    }
    __syncthreads();

#pragma unroll
    for (int kk = 0; kk < CK; ++kk) {
      int c0 = (w * CK + kk) * 32 + kseg * 8;
      float4 sa = *(const float4*)(sScl + c0);
      float4 sb = *(const float4*)(sScl + c0 + 4);
      float4 ta = *(const float4*)(sShf + c0);
      float4 tb = *(const float4*)(sShf + c0 + 4);
      bf16x8 ah[MPN], al[MPN];
#pragma unroll
      for (int m = 0; m < MPN; ++m) {
        float4 pa = *(const float4*)(pr[m] + c0);
        float4 pb = *(const float4*)(pr[m] + c0 + 4);
        float4 qa = *(const float4*)(qr[m] + c0);
        float4 qb = *(const float4*)(qr[m] + c0 + 4);
        float hv[8];
        hv[0] = fmaxf(fmaf(pa.x + qa.x, sa.x, ta.x), 0.f);
        hv[1] = fmaxf(fmaf(pa.y + qa.y, sa.y, ta.y), 0.f);
        hv[2] = fmaxf(fmaf(pa.z + qa.z, sa.z, ta.z), 0.f);
        hv[3] = fmaxf(fmaf(pa.w + qa.w, sa.w, ta.w), 0.f);
        hv[4] = fmaxf(fmaf(pb.x + qb.x, sb.x, tb.x), 0.f);
        hv[5] = fmaxf(fmaf(pb.y + qb.y, sb.y, tb.y), 0.f);
        hv[6] = fmaxf(fmaf(pb.z + qb.z, sb.z, tb.z), 0.f);
        hv[7] = fmaxf(fmaf(pb.w + qb.w, sb.w, tb.w), 0.f);
#pragma unroll
        for (int t = 0; t < 8; ++t) {
          __bf16 hb = (__bf16)hv[t];
          ah[m][t] = hb;
          al[m][t] = (__bf16)(hv[t] - (float)hb);
        }
      }
#pragma unroll
      for (int nt = 0; nt < NTS; ++nt) {
        int base = (kk * NTS + nt) * 128 + lane;
        bf16x8 bh = __builtin_bit_cast(bf16x8, ((const ushort8_alias*)Bst)[base]);
        bf16x8 bl = __builtin_bit_cast(bf16x8, ((const ushort8_alias*)Bst)[base + 64]);
#pragma unroll
        for (int m = 0; m < MPN; ++m) {
          acc[m][nt] = __builtin_amdgcn_mfma_f32_16x16x32_bf16(ah[m], bh, acc[m][nt], 0, 0, 0);
          acc[m][nt] = __builtin_amdgcn_mfma_f32_16x16x32_bf16(al[m], bh, acc[m][nt], 0, 0, 0);
          acc[m][nt] = __builtin_amdgcn_mfma_f32_16x16x32_bf16(ah[m], bl, acc[m][nt], 0, 0, 0);
        }
      }
    }
  }

  int bank = blockIdx.x & 7;
#pragma unroll
  for (int m = 0; m < MPN; ++m) {
#pragma unroll
    for (int nt = 0; nt < NTS; ++nt) {
      float s = 0.f, ss = 0.f, mx = -INFINITY, mn = INFINITY;
#pragma unroll
      for (int gi = 0; gi < 4; ++gi) {
        float zv = acc[m][nt][gi];
        s += zv; ss = fmaf(zv, zv, ss);
        mx = fmaxf(mx, zv); mn = fminf(mn, zv);
      }
      mx = fmaxf(mx, __shfl_xor(mx, 16)); mn = fminf(mn, __shfl_xor(mn, 16));
      s += __shfl_xor(s, 16); ss += __shfl_xor(ss, 16);
      mx = fmaxf(mx, __shfl_xor(mx, 32)); mn = fminf(mn, __shfl_xor(mn, 32));
      s += __shfl_xor(s, 32); ss += __shfl_xor(ss, 32);
      if (kseg == 0) {
        int colL = nt * 16 + r;
        int col = slice * NCOL + colL;
        // sign(scl2) == sign(g2[col]) since rsqrt>0 -> select now, write one z
        float gv = g2[col];
        z[(size_t)nd[m] * C + col] = (gv >= 0.f) ? mx : mn;
        atomicAdd(&sS[colL], s);
        atomicAdd(&sSS[colL], ss);
      }
    }
  }
  __syncthreads();
  if (tid < NCOL) {
    atomicAdd(&s2b[bank * 256 + slice * NCOL + tid], sS[tid]);
    atomicAdd(&ss2b[bank * 256 + slice * NCOL + tid], sSS[tid]);
  }
}

// ---------------------------------------------------------------- finalize (banked BN2 params, single-z)
__global__ __launch_bounds__(256) void finalize2_kernel(const float* __restrict__ z,
                                                        const float* __restrict__ s2b,
                                                        const float* __restrict__ ss2b,
                                                        const float* __restrict__ g2,
                                                        const float* __restrict__ e2,
                                                        float* __restrict__ out, int Cmask) {
  int t = blockIdx.x * 256 + threadIdx.x;
  int c = t & Cmask;
  float s = 0.f, ss = 0.f;
#pragma unroll
  for (int k = 0; k < 8; ++k) {
    s += s2b[k * 256 + c];
    ss += ss2b[k * 256 + c];
  }
  float mean = s / (float)MEDGE;
  float var = ss / (float)MEDGE - mean * mean;
  if (var < 0.f) var = 0.f;
  float scl = g2[c] * rsqrtf(var + 1e-5f);
  float shf = e2[c] - mean * scl;
  out[t] = fmaxf(fmaf(z[t], scl, shf), 0.f);
}

// ---------------------------------------------------------------- fused L3 finalize + pool (single-z)
__global__ __launch_bounds__(256) void fin3_pool(const float* __restrict__ z,
                                                 const float* __restrict__ s2b,
                                                 const float* __restrict__ ss2b,
                                                 const float* __restrict__ g2,
                                                 const float* __restrict__ e2,
                                                 float* __restrict__ pooled) {
  int b = blockIdx.x >> 2, cc = blockIdx.x & 3;
  int tid = threadIdx.x;
  int cl = tid & 63, ng = tid >> 6;       // 4 node-groups x 32 nodes
  int c = cc * 64 + cl;
  float s = 0.f, ss = 0.f;
#pragma unroll
  for (int k = 0; k < 8; ++k) { s += s2b[k * 256 + c]; ss += ss2b[k * 256 + c]; }
  float mean = s / (float)MEDGE;
  float var = ss / (float)MEDGE - mean * mean;
  if (var < 0.f) var = 0.f;
  float scl = g2[c] * rsqrtf(var + 1e-5f);
  float shf = e2[c] - mean * scl;

  float acc = 0.f, mx = -INFINITY;
  for (int n = ng * 32; n < ng * 32 + 32; ++n) {
    size_t t = (size_t)(b * NN + n) * 256 + c;
    float h = fmaxf(fmaf(z[t], scl, shf), 0.f);
    acc += h; mx = fmaxf(mx, h);
  }
  __shared__ float sSum[4][64], sMax[4][64];
  sSum[ng][cl] = acc; sMax[ng][cl] = mx;
  __syncthreads();
  if (ng == 0) {
    float a = sSum[0][cl] + sSum[1][cl] + sSum[2][cl] + sSum[3][cl];
    float m = fmaxf(fmaxf(sMax[0][cl], sMax[1][cl]), fmaxf(sMax[2][cl], sMax[3][cl]));
    pooled[b * 512 + c] = a * (1.f / 128.f);
    pooled[b * 512 + 256 + c] = m;
  }
}

// ---------------------------------------------------------------- FC tail
__global__ __launch_bounds__(256) void fc1_fused(const float* __restrict__ pooled,
                                                 const float* __restrict__ W,
                                                 const float* __restrict__ bias,
                                                 float* __restrict__ t1raw,
                                                 float* __restrict__ fs, float* __restrict__ fss) {
  int b = blockIdx.x, c = threadIdx.x;
  __shared__ float row[512];
  row[c] = pooled[b * 512 + c];
  row[c + 256] = pooled[b * 512 + 256 + c];
  __syncthreads();
  float acc = bias[c];
  for (int i = 0; i < 512; ++i) acc = fmaf(row[i], W[i * 256 + c], acc);
  t1raw[b * 256 + c] = acc;
  atomicAdd(&fs[c], acc);
  atomicAdd(&fss[c], acc * acc);
}

__global__ __launch_bounds__(256) void fc2_fused(const float* __restrict__ t1raw,
                                                 const float* __restrict__ fs,
                                                 const float* __restrict__ fss,
                                                 const float* __restrict__ g1,
                                                 const float* __restrict__ e1,
                                                 const float* __restrict__ W,
                                                 const float* __restrict__ bias,
                                                 float* __restrict__ t2raw,
                                                 float* __restrict__ gs, float* __restrict__ gss) {
  int b = blockIdx.x, c = threadIdx.x;
  __shared__ float row[256];
  {
    float mean = fs[c] / 128.f;
    float var = fss[c] / 128.f - mean * mean;
    if (var < 0.f) var = 0.f;
    float scl = g1[c] * rsqrtf(var + 1e-5f);
    float shf = e1[c] - mean * scl;
    row[c] = fmaxf(fmaf(t1raw[b * 256 + c], scl, shf), 0.f);
  }
  __syncthreads();
  if (c < 128) {
    float acc = bias[c];
    for (int i = 0; i < 256; ++i) acc = fmaf(row[i], W[i * 128 + c], acc);
    t2raw[b * 128 + c] = acc;
    atomicAdd(&gs[c], acc);
    atomicAdd(&gss[c], acc * acc);
  }
}

__global__ __launch_bounds__(256) void fc3_fused(const float* __restrict__ t2raw,
                                                 const float* __restrict__ gs,
                                                 const float* __restrict__ gss,
                                                 const float* __restrict__ g2,
                                                 const float* __restrict__ e2,
                                                 const float* __restrict__ W,
                                                 const float* __restrict__ bias,
                                                 float* __restrict__ out) {
  __shared__ float row[128 * 2];
  int t = threadIdx.x;
  if (t < 128) {
    float mean = gs[t] / 128.f;
    float var = gss[t] / 128.f - mean * mean;
    if (var < 0.f) var = 0.f;
    float scl = g2[t] * rsqrtf(var + 1e-5f);
    row[t] = scl;
    row[128 + t] = e2[t] - mean * scl;
  }
  __syncthreads();
  int b = t >> 1, jj = t & 1;
  float acc = bias[jj];
  for (int r = 0; r < 128; ++r) {
    float v = fmaxf(fmaf(t2raw[b * 128 + r], row[r], row[128 + r]), 0.f);
    acc = fmaf(v, W[r * 2 + jj], acc);
  }
  out[t] = acc;
}

// ---------------------------------------------------------------- per-layer driver

struct LayerPtrs {
  int* idx; float *p, *q, *z;
};

template<int Cin, int C, bool DOFIN>
static void run_edgeconv(const float* xin,
                         const float* W1, const float* b1, const float* g1, const float* e1,
                         const float* b2, const float* g2, const float* e2,
                         const u16* Wh1, const u16* Wl1, const u16* Wh2, const u16* Wl2,
                         float* hout, float* statsL, const LayerPtrs& L, hipStream_t stream) {
  float* s2b = statsL + 4096;
  float* ss2b = statsL + 6144;

  knn_fused<Cin><<<dim3(BB * 2), dim3(256), 0, stream>>>(xin, L.idx);
  if constexpr (Cin >= 16) {
    constexpr int NSL1 = (2 * C) / 64;
    node_gemm_v2<Cin, 2 * C><<<dim3((MNODE / 128) * NSL1), dim3(512), 0, stream>>>(
        xin, Wh1, Wl1, L.p, L.q);
  } else {
    node_gemm<<<dim3(MNODE / 8), dim3(C), 0, stream>>>(xin, W1, L.p, L.q, Cin, C);
  }
  edge_stats1v<C><<<dim3(MNODE / 4), dim3(256), 0, stream>>>(L.p, L.q, b1, L.idx, statsL);
  // R4-verified config: MPN=2 with acc kept at 64 regs:
  //   C=64 : NCOL=64,  NTS=4, CK=2 -> Bst 16 KB, NWIN=1, NSLICE=1
  //   C=128: NCOL=128, NTS=8, CK=4 -> Bst 64 KB, NWIN=1, NSLICE=1
  //   C=256: NCOL=128, NTS=8, CK=4 -> Bst 64 KB, NWIN=2, NSLICE=2
  constexpr int NCOL = (C == 256) ? 128 : C;
  constexpr int CKW = (C == 64) ? 2 : 4;
  constexpr int MPN = 2;
  constexpr int NSL = C / NCOL;
  edge_gemm2_v17<C, NCOL, CKW, MPN><<<dim3((MNODE / (8 * MPN)) * NSL), dim3(512), 0, stream>>>(
      L.p, L.q, L.idx, statsL, g1, e1, b1, Wh2, Wl2, b2, g2, L.z, s2b, ss2b);
  if constexpr (DOFIN) {
    finalize2_kernel<<<dim3(MNODE * C / 256), dim3(256), 0, stream>>>(
        L.z, s2b, ss2b, g2, e2, hout, C - 1);
  }
}

// ---------------------------------------------------------------- launch

extern "C" void kernel_launch(void* const* d_in, const int* in_sizes, int n_in,
                              void* d_out, int out_size, void* d_ws, size_t ws_size,
                              hipStream_t stream) {
  const float* x   = (const float*)d_in[0];
  const float* w11 = (const float*)d_in[1];
  const float* b11 = (const float*)d_in[2];
  const float* g11 = (const float*)d_in[3];
  const float* e11 = (const float*)d_in[4];
  const float* w12 = (const float*)d_in[5];
  const float* b12 = (const float*)d_in[6];
  const float* g12 = (const float*)d_in[7];
  const float* e12 = (const float*)d_in[8];
  const float* w21 = (const float*)d_in[9];
  const float* b21 = (const float*)d_in[10];
  const float* g21 = (const float*)d_in[11];
  const float* e21 = (const float*)d_in[12];
  const float* w22 = (const float*)d_in[13];
  const float* b22 = (const float*)d_in[14];
  const float* g22 = (const float*)d_in[15];
  const float* e22 = (const float*)d_in[16];
  const float* w31 = (const float*)d_in[17];
  const float* b31 = (const float*)d_in[18];
  const float* g31 = (const float*)d_in[19];
  const float* e31 = (const float*)d_in[20];
  const float* w32 = (const float*)d_in[21];
  const float* b32 = (const float*)d_in[22];
  const float* g32 = (const float*)d_in[23];
  const float* e32 = (const float*)d_in[24];
  const float* fw1 = (const float*)d_in[25];
  const float* fb1 = (const float*)d_in[26];
  const float* fg1 = (const float*)d_in[27];
  const float* fe1 = (const float*)d_in[28];
  const float* fw2 = (const float*)d_in[29];
  const float* fb2 = (const float*)d_in[30];
  const float* fg2 = (const float*)d_in[31];
  const float* fe2 = (const float*)d_in[32];
  const float* fw3 = (const float*)d_in[33];
  const float* fb3 = (const float*)d_in[34];

  char* wsb = (char*)d_ws;
  size_t o = 0;
  auto alloc = [&](size_t bytes) -> void* {
    void* r = wsb + o;
    o += (bytes + 255) & ~(size_t)255;
    return r;
  };
  LayerPtrs L;
  L.idx   = (int*)  alloc((size_t)MNODE * KK * sizeof(int));
  L.p     = (float*)alloc((size_t)MNODE * 256 * sizeof(float));
  L.q     = (float*)alloc((size_t)MNODE * 256 * sizeof(float));
  L.z     = (float*)alloc((size_t)MNODE * 256 * sizeof(float));
  // per-layer packed weights (filled once by pack_all)
  u16* h12 = (u16*)alloc(64 * 64 * sizeof(u16));
  u16* l12 = (u16*)alloc(64 * 64 * sizeof(u16));
  u16* h22 = (u16*)alloc(128 * 128 * sizeof(u16));
  u16* l22 = (u16*)alloc(128 * 128 * sizeof(u16));
  u16* h32 = (u16*)alloc(256 * 256 * sizeof(u16));
  u16* l32 = (u16*)alloc(256 * 256 * sizeof(u16));
  u16* h21 = (u16*)alloc(64 * 256 * sizeof(u16));
  u16* l21 = (u16*)alloc(64 * 256 * sizeof(u16));
  u16* h31 = (u16*)alloc(128 * 512 * sizeof(u16));
  u16* l31 = (u16*)alloc(128 * 512 * sizeof(u16));
  float* statsAll = (float*)alloc((3 * 8192 + 1024) * sizeof(float));
  float* h1buf   = (float*)alloc((size_t)MNODE * 64 * sizeof(float));
  float* h2buf   = (float*)alloc((size_t)MNODE * 128 * sizeof(float));
  float* pooled  = (float*)alloc(128 * 512 * sizeof(float));
  float* t1raw   = (float*)alloc(128 * 256 * sizeof(float));
  float* t2raw   = (float*)alloc(128 * 128 * sizeof(float));

  float* fcstats = statsAll + 3 * 8192;
  float* fs  = fcstats;
  float* fss = fcstats + 256;
  float* gs  = fcstats + 512;
  float* gss = fcstats + 768;

  (void)hipMemsetAsync(statsAll, 0, (3 * 8192 + 1024) * sizeof(float), stream);
  pack_all<<<dim3(656), dim3(256), 0, stream>>>(w12, w22, w32, w21, w31,
      h12, l12, h22, l22, h32, l32, h21, l21, h31, l31);

  run_edgeconv<6, 64, true>(x, w11, b11, g11, e11, b12, g12, e12,
                            nullptr, nullptr, h12, l12,
                            h1buf, statsAll, L, stream);
  run_edgeconv<64, 128, true>(h1buf, nullptr, b21, g21, e21, b22, g22, e22,
                              h21, l21, h22, l22,
                              h2buf, statsAll + 8192, L, stream);
  run_edgeconv<128, 256, false>(h2buf, nullptr, b31, g31, e31, b32, g32, e32,
                                h31, l31, h32, l32,
                                nullptr, statsAll + 16384, L, stream);

  // fused finalize(L3) + pool, straight into pooled (h3 never materialized)
  {
    float* s2b3 = statsAll + 16384 + 4096;
    float* ss2b3 = statsAll + 16384 + 6144;
    fin3_pool<<<dim3(BB * 4), dim3(256), 0, stream>>>(L.z, s2b3, ss2b3,
                                                      g32, e32, pooled);
  }
  fc1_fused<<<dim3(BB), dim3(256), 0, stream>>>(pooled, fw1, fb1, t1raw, fs, fss);
  fc2_fused<<<dim3(BB), dim3(256), 0, stream>>>(t1raw, fs, fss, fg1, fe1, fw2, fb2, t2raw, gs, gss);
  fc3_fused<<<dim3(1), dim3(256), 0, stream>>>(t2raw, gs, gss, fg2, fe2, fw3, fb3, (float*)d_out);
}

// Round 9
// 621.771 us; speedup vs baseline: 3.2797x; 1.0011x over previous
//
#include <hip/hip_runtime.h>
#include <math.h>

#define BB 128
#define NN 128
#define KK 16
#define MEDGE (BB*NN*KK)   // 262144 edges
#define MNODE (BB*NN)      // 16384 nodes

typedef __bf16 bf16x8 __attribute__((ext_vector_type(8)));
typedef float  floatx4 __attribute__((ext_vector_type(4)));
typedef unsigned short u16;
typedef u16 ushort8_alias __attribute__((ext_vector_type(8)));

// ---------------------------------------------------------------- utilities

__device__ __forceinline__ unsigned ord32(float f) {
  unsigned u = __float_as_uint(f);
  return (u & 0x80000000u) ? ~u : (u | 0x80000000u);
}

__device__ __forceinline__ u16 bf16_rne_bits(float x) {
  unsigned u = __float_as_uint(x);
  return (u16)((u + 0x7FFF + ((u >> 16) & 1)) >> 16);
}

// ---------------------------------------------------------------- fused kNN (dist + ballot-radix select)
// BN=true: input is the previous layer's raw GEMM output z; h = relu(fma(z,
// scl, shf)) is computed on the fly at staging time (bit-identical to the
// removed finalize2 pass: same f32 op order).
template<int C, bool BN>
__global__ __launch_bounds__(256) void knn_fused(const float* __restrict__ x,
                                                 const float* __restrict__ scl,
                                                 const float* __restrict__ shf,
                                                 int* __restrict__ idx) {
  constexpr int S = C + 2;
  constexpr int DS = NN + 2;
  constexpr int XSZ = (NN * S > 64 * DS) ? NN * S : 64 * DS;   // union sizing
  constexpr int CSZ = BN ? C : 1;
  __shared__ float xs[XSZ];   // x staging, then reused as Dl[64 * DS]
  __shared__ float sq[NN];
  __shared__ float kScl[CSZ], kShf[CSZ];
  int b = blockIdx.x >> 1, half = blockIdx.x & 1;
  const float* xb = x + (size_t)b * NN * C;
  int tid = threadIdx.x;

  if constexpr (BN) {
    if (tid < C) { kScl[tid] = scl[tid]; kShf[tid] = shf[tid]; }
    __syncthreads();
  }
  for (int t = tid; t < NN * C; t += 256) {
    int row = t / C, c = t - row * C;
    float v = xb[t];
    if constexpr (BN) v = fmaxf(fmaf(v, kScl[c], kShf[c]), 0.f);
    xs[row * S + c] = v;
  }
  __syncthreads();
  if (tid < NN) {
    const float* xr = xs + tid * S;
    float s = 0.f;
    for (int c = 0; c < C; ++c) s = fmaf(xr[c], xr[c], s);
    sq[tid] = s;
  }
  __syncthreads();

  // dist: 64 rows x 128 cols; thread = 8 rows x 4 cols (in registers)
  int rg = tid >> 5, cg = tid & 31;
  int r0 = half * 64 + rg * 8;
  float acc[8][4];
#pragma unroll
  for (int i = 0; i < 8; ++i)
#pragma unroll
    for (int j = 0; j < 4; ++j) acc[i][j] = 0.f;
  for (int c = 0; c < C; c += 2) {
    float2 av[8], bv[4];
#pragma unroll
    for (int i = 0; i < 8; ++i) av[i] = *(const float2*)&xs[(r0 + i) * S + c];
#pragma unroll
    for (int j = 0; j < 4; ++j) bv[j] = *(const float2*)&xs[(cg + 32 * j) * S + c];
#pragma unroll
    for (int i = 0; i < 8; ++i)
#pragma unroll
      for (int j = 0; j < 4; ++j) {
        acc[i][j] = fmaf(av[i].x, bv[j].x, acc[i][j]);
        acc[i][j] = fmaf(av[i].y, bv[j].y, acc[i][j]);
      }
  }
  float dv[8][4];
#pragma unroll
  for (int i = 0; i < 8; ++i) {
    float sn = sq[r0 + i];
#pragma unroll
    for (int j = 0; j < 4; ++j) dv[i][j] = sn - 2.f * acc[i][j] + sq[cg + 32 * j];
  }
  __syncthreads();  // all reads of xs complete
  float* Dl = xs;
#pragma unroll
  for (int i = 0; i < 8; ++i)
#pragma unroll
    for (int j = 0; j < 4; ++j)
      Dl[(rg * 8 + i) * DS + (cg + 32 * j)] = dv[i][j];
  __syncthreads();

  int lane = tid & 63, wv = tid >> 6;
  unsigned long long lmaskLT = (1ull << lane) - 1ull;   // bits below my lane
  for (int t = 0; t < 16; ++t) {
    int lr = wv * 16 + t;
    int nd = b * NN + half * 64 + lr;
    unsigned k0 = ord32(Dl[lr * DS + lane]);
    unsigned k1 = ord32(Dl[lr * DS + lane + 64]);
    int* out = idx + (size_t)nd * KK;

    // radix search: find the (32-bd)-bit prefix of the 16th-smallest key
    unsigned prefix = 0;
    int remaining = KK;      // how many still to take inside current group
    int G = 2 * 64;          // current prefix-group size
    int bd = 32;
    while (bd > 0) {
      --bd;
      unsigned pp = prefix << 1;
      bool m0 = (k0 >> bd) == pp;
      bool m1 = (k1 >> bd) == pp;
      int cnt0 = __popcll(__ballot(m0)) + __popcll(__ballot(m1));
      if (remaining <= cnt0) { prefix = pp; G = cnt0; }
      else                   { remaining -= cnt0; prefix = pp | 1; G -= cnt0; }
      if (G == remaining) break;   // whole group selected; low bits irrelevant
    }

    // emit: all keys strictly below the group + lowest-index `remaining` ties
    bool lt0 = (k0 >> bd) < prefix, eq0 = (k0 >> bd) == prefix;
    bool lt1 = (k1 >> bd) < prefix, eq1 = (k1 >> bd) == prefix;
    unsigned long long e0 = __ballot(eq0), e1 = __ballot(eq1);
    int c0 = __popcll(e0);
    int r0t = __popcll(e0 & lmaskLT);
    int r1t = c0 + __popcll(e1 & lmaskLT);
    bool s0 = lt0 || (eq0 && (r0t < remaining));
    bool s1 = lt1 || (eq1 && (r1t < remaining));
    unsigned long long S0 = __ballot(s0), S1 = __ballot(s1);
    int pos0 = __popcll(S0 & lmaskLT);
    int pos1 = __popcll(S0) + __popcll(S1 & lmaskLT);
    if (s0) out[pos0] = lane;
    if (s1) out[pos1] = lane + 64;
  }
}

// ---------------------------------------------------------------- node GEMM (scalar, layer-1 only)
__global__ __launch_bounds__(256) void node_gemm(const float* __restrict__ x,
                                                 const float* __restrict__ W,
                                                 float* __restrict__ p, float* __restrict__ q,
                                                 int Cin, int Cout) {
  int c = threadIdx.x;
  __shared__ float xr[128];
  for (int r = 0; r < 8; ++r) {
    int row = blockIdx.x * 8 + r;
    __syncthreads();
    for (int i = c; i < Cin; i += blockDim.x) xr[i] = x[(size_t)row * Cin + i];
    __syncthreads();
    float a = 0.f, qv = 0.f;
    for (int i = 0; i < Cin; ++i) {
      float xv = xr[i];
      a  = fmaf(xv, W[i * Cout + c], a);
      qv = fmaf(xv, W[(Cin + i) * Cout + c], qv);
    }
    p[(size_t)row * Cout + c] = a - qv;
    q[(size_t)row * Cout + c] = qv;
  }
}

// ---------------------------------------------------------------- weight packing (device bodies)
template<int K, int N>
__device__ __forceinline__ void pack1_body(const float* __restrict__ W1,
                                           u16* __restrict__ Wh, u16* __restrict__ Wl,
                                           int blk, int tidx) {
  int t = blk * 256 + tidx;
  if (t >= K * N) return;
  constexpr int C = N / 2;
  constexpr int NT = N / 16;
  int j = t & 7, lane = (t >> 3) & 63, tile = t >> 9;
  int nt = tile % NT, kt = tile / NT;
  int row = kt * 32 + (lane >> 4) * 8 + j;
  int col = nt * 16 + (lane & 15);
  float w;
  if (col < C) w = W1[row * C + col] - W1[(K + row) * C + col];
  else         w = W1[(K + row) * C + (col - C)];
  u16 h = bf16_rne_bits(w);
  float hf = __uint_as_float(((unsigned)h) << 16);
  Wh[t] = h;
  Wl[t] = bf16_rne_bits(w - hf);
}

template<int C>
__device__ __forceinline__ void pack2_body(const float* __restrict__ W,
                                           u16* __restrict__ Wh, u16* __restrict__ Wl,
                                           int blk, int tidx) {
  int t = blk * 256 + tidx;
  if (t >= C * C) return;
  constexpr int NT = C / 16;
  int j = t & 7, lane = (t >> 3) & 63, tile = t >> 9;
  int nt = tile % NT, kt = tile / NT;
  int row = kt * 32 + (lane >> 4) * 8 + j;
  int col = nt * 16 + (lane & 15);
  float w = W[row * C + col];
  u16 h = bf16_rne_bits(w);
  float hf = __uint_as_float(((unsigned)h) << 16);
  Wh[t] = h;
  Wl[t] = bf16_rne_bits(w - hf);
}

// one dispatch packs all 5 weight matrices into per-layer buffers
__global__ __launch_bounds__(256) void pack_all(
    const float* __restrict__ w12, const float* __restrict__ w22, const float* __restrict__ w32,
    const float* __restrict__ w21, const float* __restrict__ w31,
    u16* h12, u16* l12, u16* h22, u16* l22, u16* h32, u16* l32,
    u16* h21, u16* l21, u16* h31, u16* l31) {
  int blk = blockIdx.x, tidx = threadIdx.x;
  if (blk < 16)        pack2_body<64 >(w12, h12, l12, blk,        tidx);
  else if (blk < 80)   pack2_body<128>(w22, h22, l22, blk - 16,   tidx);
  else if (blk < 336)  pack2_body<256>(w32, h32, l32, blk - 80,   tidx);
  else if (blk < 400)  pack1_body<64, 256>(w21, h21, l21, blk - 336, tidx);
  else                 pack1_body<128, 512>(w31, h31, l31, blk - 400, tidx);
}

// ---------------------------------------------------------------- node GEMM v2 (v9-style; BN-on-load)
template<int K, int N, bool BN>
__global__ __launch_bounds__(512, 4) void node_gemm_v2(
    const float* __restrict__ x, const u16* __restrict__ Wh, const u16* __restrict__ Wl,
    const float* __restrict__ scl, const float* __restrict__ shf,
    float* __restrict__ p, float* __restrict__ q) {
  constexpr int C = N / 2;
  constexpr int KT = K / 32;
  constexpr int NT = N / 16;
  constexpr int NCOL = 64, NTS = 4;
  constexpr int NSLICE = N / 64;
  constexpr int CCH = KT * NTS * 2 * 64;
  constexpr int KSZ = BN ? K : 1;
  __shared__ __align__(16) u16 Bst[CCH * 8];
  __shared__ float sScl[KSZ], sShf[KSZ];

  int tid = threadIdx.x, lane = tid & 63, wv = tid >> 6;
  int r = lane & 15, kseg = lane >> 4;
  int g = blockIdx.x / NSLICE, slice = blockIdx.x % NSLICE;
  int rowBase = g * 128 + wv * 16;
  const float* xr = x + (size_t)(rowBase + r) * K;

  if constexpr (BN) {
    if (tid < K) { sScl[tid] = scl[tid]; sShf[tid] = shf[tid]; }
  }
  for (int i = tid; i < CCH; i += 512) {
    int c = i & 63, h = (i >> 6) & 1, rest = i >> 7;
    int nt = rest % NTS, kt = rest / NTS;
    const ushort8_alias* src = h ? (const ushort8_alias*)Wl : (const ushort8_alias*)Wh;
    ((ushort8_alias*)Bst)[i] = src[((size_t)kt * NT + slice * NTS + nt) * 64 + c];
  }
  __syncthreads();

  floatx4 acc[NTS];
#pragma unroll
  for (int nt = 0; nt < NTS; ++nt) acc[nt] = {0.f, 0.f, 0.f, 0.f};

#pragma unroll
  for (int kt = 0; kt < KT; ++kt) {
    int c0 = kt * 32 + kseg * 8;
    float4 xa = *(const float4*)(xr + c0);
    float4 xb = *(const float4*)(xr + c0 + 4);
    float hv[8] = {xa.x, xa.y, xa.z, xa.w, xb.x, xb.y, xb.z, xb.w};
    if constexpr (BN) {
#pragma unroll
      for (int t = 0; t < 8; ++t)
        hv[t] = fmaxf(fmaf(hv[t], sScl[c0 + t], sShf[c0 + t]), 0.f);
    }
    bf16x8 ah, al;
#pragma unroll
    for (int t = 0; t < 8; ++t) {
      __bf16 hb = (__bf16)hv[t];
      ah[t] = hb;
      al[t] = (__bf16)(hv[t] - (float)hb);
    }
#pragma unroll
    for (int nt = 0; nt < NTS; ++nt) {
      int base = (kt * NTS + nt) * 128 + lane;
      bf16x8 bh = __builtin_bit_cast(bf16x8, ((const ushort8_alias*)Bst)[base]);
      bf16x8 bl = __builtin_bit_cast(bf16x8, ((const ushort8_alias*)Bst)[base + 64]);
      acc[nt] = __builtin_amdgcn_mfma_f32_16x16x32_bf16(ah, bh, acc[nt], 0, 0, 0);
      acc[nt] = __builtin_amdgcn_mfma_f32_16x16x32_bf16(al, bh, acc[nt], 0, 0, 0);
      acc[nt] = __builtin_amdgcn_mfma_f32_16x16x32_bf16(ah, bl, acc[nt], 0, 0, 0);
    }
  }

#pragma unroll
  for (int nt = 0; nt < NTS; ++nt) {
    int n = slice * NCOL + nt * 16 + r;
    float* dst = (n < C) ? p : q;
    int col = (n < C) ? n : n - C;
#pragma unroll
    for (int gi = 0; gi < 4; ++gi) {
      int row = rowBase + kseg * 4 + gi;
      dst[(size_t)row * C + col] = acc[nt][gi];
    }
  }
}

// ---------------------------------------------------------------- BN1 stats (banked atomics)
template<int C>
__global__ __launch_bounds__(256) void edge_stats1v(const float* __restrict__ p,
                                                    const float* __restrict__ q,
                                                    const float* __restrict__ b1,
                                                    const int* __restrict__ idx,
                                                    float* __restrict__ statsL) {
  constexpr int G = C / 4;
  constexpr int KL = 64 / G;
  int tid = threadIdx.x, lane = tid & 63, wv = tid >> 6;
  int nd = blockIdx.x * 4 + wv;
  int b = nd >> 7;
  int g = lane % G, kl = lane / G;
  int bank = blockIdx.x & 7;

  __shared__ float sS[C], sSS[C];
  if (tid < C) { sS[tid] = 0.f; sSS[tid] = 0.f; }
  __syncthreads();

  const float* pr = p + (size_t)nd * C;
  float4 pv = *(const float4*)(pr + g * 4);
  float4 bv = *(const float4*)(b1 + g * 4);
  pv.x += bv.x; pv.y += bv.y; pv.z += bv.z; pv.w += bv.w;
  float4 s = {0, 0, 0, 0}, ss = {0, 0, 0, 0};
  const int* id = idx + (size_t)nd * KK;
#pragma unroll
  for (int k0 = 0; k0 < KK; k0 += KL) {
    int j = id[k0 + kl];
    float4 q4 = *(const float4*)(q + (size_t)(b * NN + j) * C + g * 4);
    float y;
    y = pv.x + q4.x; s.x += y; ss.x = fmaf(y, y, ss.x);
    y = pv.y + q4.y; s.y += y; ss.y = fmaf(y, y, ss.y);
    y = pv.z + q4.z; s.z += y; ss.z = fmaf(y, y, ss.z);
    y = pv.w + q4.w; s.w += y; ss.w = fmaf(y, y, ss.w);
  }
#pragma unroll
  for (int off = G; off < 64; off <<= 1) {
    s.x += __shfl_xor(s.x, off); ss.x += __shfl_xor(ss.x, off);
    s.y += __shfl_xor(s.y, off); ss.y += __shfl_xor(ss.y, off);
    s.z += __shfl_xor(s.z, off); ss.z += __shfl_xor(ss.z, off);
    s.w += __shfl_xor(s.w, off); ss.w += __shfl_xor(ss.w, off);
  }
  if (kl == 0) {
    atomicAdd(&sS[g * 4 + 0], s.x); atomicAdd(&sSS[g * 4 + 0], ss.x);
    atomicAdd(&sS[g * 4 + 1], s.y); atomicAdd(&sSS[g * 4 + 1], ss.y);
    atomicAdd(&sS[g * 4 + 2], s.z); atomicAdd(&sSS[g * 4 + 2], ss.z);
    atomicAdd(&sS[g * 4 + 3], s.w); atomicAdd(&sSS[g * 4 + 3], ss.w);
  }
  __syncthreads();
  if (tid < C) {
    atomicAdd(&statsL[bank * 256 + tid], sS[tid]);
    atomicAdd(&statsL[2048 + bank * 256 + tid], sSS[tid]);
  }
}

// ---------------------------------------------------------------- MFMA edge GEMM2 v17 (R8-verified)
template<int C, int NCOL, int CK, int MPN>
__global__ __launch_bounds__(512, 4) void edge_gemm2_v17(
    const float* __restrict__ p, const float* __restrict__ q,
    const int* __restrict__ idx,
    const float* __restrict__ statsL,
    const float* __restrict__ g1, const float* __restrict__ e1,
    const float* __restrict__ b1,
    const u16* __restrict__ Wh, const u16* __restrict__ Wl,
    const float* __restrict__ b2, const float* __restrict__ g2,
    float* __restrict__ z,
    float* __restrict__ s2b, float* __restrict__ ss2b) {
  constexpr int KT = C / 32;
  constexpr int NT = C / 16;
  constexpr int NSLICE = C / NCOL;
  constexpr int NTS = NCOL / 16;
  constexpr int NWIN = KT / CK;
  constexpr int CCH = CK * NTS * 2 * 64;
  constexpr int NPB = 8 * MPN;       // nodes per block
  constexpr int GPB = NN / NPB;      // node-groups per batch
  __shared__ __align__(16) u16 Bst[CCH * 8];
  __shared__ float sScl[C], sShf[C];
  __shared__ float sS[NCOL], sSS[NCOL];

  int tid = threadIdx.x, lane = tid & 63, wv = tid >> 6;
  int r = lane & 15, kseg = lane >> 4;

  int g = blockIdx.x / NSLICE, slice = blockIdx.x % NSLICE;
  int u = g >> 3, xcd = g & 7;
  int b = xcd + 8 * (u / GPB);
  int nodeBase = b * NN + (u % GPB) * NPB;

  if (tid < C) {
    float s = 0.f, ssum = 0.f;
#pragma unroll
    for (int k = 0; k < 8; ++k) {
      s += statsL[k * 256 + tid];
      ssum += statsL[2048 + k * 256 + tid];
    }
    float mean = s / (float)MEDGE;
    float var = ssum / (float)MEDGE - mean * mean;
    if (var < 0.f) var = 0.f;
    float sc = g1[tid] * rsqrtf(var + 1e-5f);
    sScl[tid] = sc;
    sShf[tid] = e1[tid] - mean * sc + sc * b1[tid];
  }
  if (tid < NCOL) { sS[tid] = 0.f; sSS[tid] = 0.f; }

  int nd[MPN];
  const float *pr[MPN], *qr[MPN];
#pragma unroll
  for (int m = 0; m < MPN; ++m) {
    nd[m] = nodeBase + wv * MPN + m;
    int j = idx[(size_t)nd[m] * KK + r];
    pr[m] = p + (size_t)nd[m] * C;
    qr[m] = q + (size_t)(b * NN + j) * C;
  }

  floatx4 acc[MPN][NTS];
#pragma unroll
  for (int nt = 0; nt < NTS; ++nt) {
    float bv = b2[slice * NCOL + nt * 16 + r];
#pragma unroll
    for (int m = 0; m < MPN; ++m) acc[m][nt] = {bv, bv, bv, bv};
  }

#pragma unroll
  for (int w = 0; w < NWIN; ++w) {
    if (w > 0) __syncthreads();
    for (int i = tid; i < CCH; i += 512) {
      int c = i & 63, h = (i >> 6) & 1, rest = i >> 7;
      int nt = rest % NTS, kk = rest / NTS;
      const ushort8_alias* src = h ? (const ushort8_alias*)Wl : (const ushort8_alias*)Wh;
      ((ushort8_alias*)Bst)[i] = src[((size_t)(w * CK + kk) * NT + slice * NTS + nt) * 64 + c];
    }
    __syncthreads();

#pragma unroll
    for (int kk = 0; kk < CK; ++kk) {
      int c0 = (w * CK + kk) * 32 + kseg * 8;
      float4 sa = *(const float4*)(sScl + c0);
      float4 sb = *(const float4*)(sScl + c0 + 4);
      float4 ta = *(const float4*)(sShf + c0);
      float4 tb = *(const float4*)(sShf + c0 + 4);
      bf16x8 ah[MPN], al[MPN];
#pragma unroll
      for (int m = 0; m < MPN; ++m) {
        float4 pa = *(const float4*)(pr[m] + c0);
        float4 pb = *(const float4*)(pr[m] + c0 + 4);
        float4 qa = *(const float4*)(qr[m] + c0);
        float4 qb = *(const float4*)(qr[m] + c0 + 4);
        float hv[8];
        hv[0] = fmaxf(fmaf(pa.x + qa.x, sa.x, ta.x), 0.f);
        hv[1] = fmaxf(fmaf(pa.y + qa.y, sa.y, ta.y), 0.f);
        hv[2] = fmaxf(fmaf(pa.z + qa.z, sa.z, ta.z), 0.f);
        hv[3] = fmaxf(fmaf(pa.w + qa.w, sa.w, ta.w), 0.f);
        hv[4] = fmaxf(fmaf(pb.x + qb.x, sb.x, tb.x), 0.f);
        hv[5] = fmaxf(fmaf(pb.y + qb.y, sb.y, tb.y), 0.f);
        hv[6] = fmaxf(fmaf(pb.z + qb.z, sb.z, tb.z), 0.f);
        hv[7] = fmaxf(fmaf(pb.w + qb.w, sb.w, tb.w), 0.f);
#pragma unroll
        for (int t = 0; t < 8; ++t) {
          __bf16 hb = (__bf16)hv[t];
          ah[m][t] = hb;
          al[m][t] = (__bf16)(hv[t] - (float)hb);
        }
      }
#pragma unroll
      for (int nt = 0; nt < NTS; ++nt) {
        int base = (kk * NTS + nt) * 128 + lane;
        bf16x8 bh = __builtin_bit_cast(bf16x8, ((const ushort8_alias*)Bst)[base]);
        bf16x8 bl = __builtin_bit_cast(bf16x8, ((const ushort8_alias*)Bst)[base + 64]);
#pragma unroll
        for (int m = 0; m < MPN; ++m) {
          acc[m][nt] = __builtin_amdgcn_mfma_f32_16x16x32_bf16(ah[m], bh, acc[m][nt], 0, 0, 0);
          acc[m][nt] = __builtin_amdgcn_mfma_f32_16x16x32_bf16(al[m], bh, acc[m][nt], 0, 0, 0);
          acc[m][nt] = __builtin_amdgcn_mfma_f32_16x16x32_bf16(ah[m], bl, acc[m][nt], 0, 0, 0);
        }
      }
    }
  }

  int bank = blockIdx.x & 7;
#pragma unroll
  for (int m = 0; m < MPN; ++m) {
#pragma unroll
    for (int nt = 0; nt < NTS; ++nt) {
      float s = 0.f, ss = 0.f, mx = -INFINITY, mn = INFINITY;
#pragma unroll
      for (int gi = 0; gi < 4; ++gi) {
        float zv = acc[m][nt][gi];
        s += zv; ss = fmaf(zv, zv, ss);
        mx = fmaxf(mx, zv); mn = fminf(mn, zv);
      }
      mx = fmaxf(mx, __shfl_xor(mx, 16)); mn = fminf(mn, __shfl_xor(mn, 16));
      s += __shfl_xor(s, 16); ss += __shfl_xor(ss, 16);
      mx = fmaxf(mx, __shfl_xor(mx, 32)); mn = fminf(mn, __shfl_xor(mn, 32));
      s += __shfl_xor(s, 32); ss += __shfl_xor(ss, 32);
      if (kseg == 0) {
        int colL = nt * 16 + r;
        int col = slice * NCOL + colL;
        // sign(scl2) == sign(g2[col]) since rsqrt>0 -> select now, write one z
        float gv = g2[col];
        z[(size_t)nd[m] * C + col] = (gv >= 0.f) ? mx : mn;
        atomicAdd(&sS[colL], s);
        atomicAdd(&sSS[colL], ss);
      }
    }
  }
  __syncthreads();
  if (tid < NCOL) {
    atomicAdd(&s2b[bank * 256 + slice * NCOL + tid], sS[tid]);
    atomicAdd(&ss2b[bank * 256 + slice * NCOL + tid], sSS[tid]);
  }
}

// ---------------------------------------------------------------- BN2 params (replaces finalize2's bulk pass)
template<int C>
__global__ __launch_bounds__(256) void bn2params(const float* __restrict__ s2b,
                                                 const float* __restrict__ ss2b,
                                                 const float* __restrict__ g2,
                                                 const float* __restrict__ e2,
                                                 float* __restrict__ scl,
                                                 float* __restrict__ shf) {
  int c = threadIdx.x;
  if (c >= C) return;
  float s = 0.f, ss = 0.f;
#pragma unroll
  for (int k = 0; k < 8; ++k) {
    s += s2b[k * 256 + c];
    ss += ss2b[k * 256 + c];
  }
  float mean = s / (float)MEDGE;
  float var = ss / (float)MEDGE - mean * mean;
  if (var < 0.f) var = 0.f;
  float sc = g2[c] * rsqrtf(var + 1e-5f);
  scl[c] = sc;
  shf[c] = e2[c] - mean * sc;
}

// ---------------------------------------------------------------- fused L3 finalize + pool (single-z)
__global__ __launch_bounds__(256) void fin3_pool(const float* __restrict__ z,
                                                 const float* __restrict__ s2b,
                                                 const float* __restrict__ ss2b,
                                                 const float* __restrict__ g2,
                                                 const float* __restrict__ e2,
                                                 float* __restrict__ pooled) {
  int b = blockIdx.x >> 2, cc = blockIdx.x & 3;
  int tid = threadIdx.x;
  int cl = tid & 63, ng = tid >> 6;       // 4 node-groups x 32 nodes
  int c = cc * 64 + cl;
  float s = 0.f, ss = 0.f;
#pragma unroll
  for (int k = 0; k < 8; ++k) { s += s2b[k * 256 + c]; ss += ss2b[k * 256 + c]; }
  float mean = s / (float)MEDGE;
  float var = ss / (float)MEDGE - mean * mean;
  if (var < 0.f) var = 0.f;
  float scl = g2[c] * rsqrtf(var + 1e-5f);
  float shf = e2[c] - mean * scl;

  float acc = 0.f, mx = -INFINITY;
  for (int n = ng * 32; n < ng * 32 + 32; ++n) {
    size_t t = (size_t)(b * NN + n) * 256 + c;
    float h = fmaxf(fmaf(z[t], scl, shf), 0.f);
    acc += h; mx = fmaxf(mx, h);
  }
  __shared__ float sSum[4][64], sMax[4][64];
  sSum[ng][cl] = acc; sMax[ng][cl] = mx;
  __syncthreads();
  if (ng == 0) {
    float a = sSum[0][cl] + sSum[1][cl] + sSum[2][cl] + sSum[3][cl];
    float m = fmaxf(fmaxf(sMax[0][cl], sMax[1][cl]), fmaxf(sMax[2][cl], sMax[3][cl]));
    pooled[b * 512 + c] = a * (1.f / 128.f);
    pooled[b * 512 + 256 + c] = m;
  }
}

// ---------------------------------------------------------------- FC tail
__global__ __launch_bounds__(256) void fc1_fused(const float* __restrict__ pooled,
                                                 const float* __restrict__ W,
                                                 const float* __restrict__ bias,
                                                 float* __restrict__ t1raw,
                                                 float* __restrict__ fs, float* __restrict__ fss) {
  int b = blockIdx.x, c = threadIdx.x;
  __shared__ float row[512];
  row[c] = pooled[b * 512 + c];
  row[c + 256] = pooled[b * 512 + 256 + c];
  __syncthreads();
  float acc = bias[c];
  for (int i = 0; i < 512; ++i) acc = fmaf(row[i], W[i * 256 + c], acc);
  t1raw[b * 256 + c] = acc;
  atomicAdd(&fs[c], acc);
  atomicAdd(&fss[c], acc * acc);
}

__global__ __launch_bounds__(256) void fc2_fused(const float* __restrict__ t1raw,
                                                 const float* __restrict__ fs,
                                                 const float* __restrict__ fss,
                                                 const float* __restrict__ g1,
                                                 const float* __restrict__ e1,
                                                 const float* __restrict__ W,
                                                 const float* __restrict__ bias,
                                                 float* __restrict__ t2raw,
                                                 float* __restrict__ gs, float* __restrict__ gss) {
  int b = blockIdx.x, c = threadIdx.x;
  __shared__ float row[256];
  {
    float mean = fs[c] / 128.f;
    float var = fss[c] / 128.f - mean * mean;
    if (var < 0.f) var = 0.f;
    float scl = g1[c] * rsqrtf(var + 1e-5f);
    float shf = e1[c] - mean * scl;
    row[c] = fmaxf(fmaf(t1raw[b * 256 + c], scl, shf), 0.f);
  }
  __syncthreads();
  if (c < 128) {
    float acc = bias[c];
    for (int i = 0; i < 256; ++i) acc = fmaf(row[i], W[i * 128 + c], acc);
    t2raw[b * 128 + c] = acc;
    atomicAdd(&gs[c], acc);
    atomicAdd(&gss[c], acc * acc);
  }
}

__global__ __launch_bounds__(256) void fc3_fused(const float* __restrict__ t2raw,
                                                 const float* __restrict__ gs,
                                                 const float* __restrict__ gss,
                                                 const float* __restrict__ g2,
                                                 const float* __restrict__ e2,
                                                 const float* __restrict__ W,
                                                 const float* __restrict__ bias,
                                                 float* __restrict__ out) {
  __shared__ float row[128 * 2];
  int t = threadIdx.x;
  if (t < 128) {
    float mean = gs[t] / 128.f;
    float var = gss[t] / 128.f - mean * mean;
    if (var < 0.f) var = 0.f;
    float scl = g2[t] * rsqrtf(var + 1e-5f);
    row[t] = scl;
    row[128 + t] = e2[t] - mean * scl;
  }
  __syncthreads();
  int b = t >> 1, jj = t & 1;
  float acc = bias[jj];
  for (int r = 0; r < 128; ++r) {
    float v = fmaxf(fmaf(t2raw[b * 128 + r], row[r], row[128 + r]), 0.f);
    acc = fmaf(v, W[r * 2 + jj], acc);
  }
  out[t] = acc;
}

// ---------------------------------------------------------------- per-layer driver

struct LayerPtrs {
  int* idx; float *p, *q, *z;
  float *scl2, *shf2;
};

template<int Cin, int C, bool BNIN, bool DOFIN>
static void run_edgeconv(const float* xin, const float* sclIn, const float* shfIn,
                         const float* W1, const float* b1, const float* g1, const float* e1,
                         const float* b2, const float* g2, const float* e2,
                         const u16* Wh1, const u16* Wl1, const u16* Wh2, const u16* Wl2,
                         float* statsL, const LayerPtrs& L, hipStream_t stream) {
  float* s2b = statsL + 4096;
  float* ss2b = statsL + 6144;

  knn_fused<Cin, BNIN><<<dim3(BB * 2), dim3(256), 0, stream>>>(xin, sclIn, shfIn, L.idx);
  if constexpr (Cin >= 16) {
    constexpr int NSL1 = (2 * C) / 64;
    node_gemm_v2<Cin, 2 * C, BNIN><<<dim3((MNODE / 128) * NSL1), dim3(512), 0, stream>>>(
        xin, Wh1, Wl1, sclIn, shfIn, L.p, L.q);
  } else {
    node_gemm<<<dim3(MNODE / 8), dim3(C), 0, stream>>>(xin, W1, L.p, L.q, Cin, C);
  }
  edge_stats1v<C><<<dim3(MNODE / 4), dim3(256), 0, stream>>>(L.p, L.q, b1, L.idx, statsL);
  // R4/R8-verified config: MPN=2 with acc kept at 64 regs:
  //   C=64 : NCOL=64,  NTS=4, CK=2 -> Bst 16 KB, NWIN=1, NSLICE=1
  //   C=128: NCOL=128, NTS=8, CK=4 -> Bst 64 KB, NWIN=1, NSLICE=1
  //   C=256: NCOL=128, NTS=8, CK=4 -> Bst 64 KB, NWIN=2, NSLICE=2
  constexpr int NCOL = (C == 256) ? 128 : C;
  constexpr int CKW = (C == 64) ? 2 : 4;
  constexpr int MPN = 2;
  constexpr int NSL = C / NCOL;
  edge_gemm2_v17<C, NCOL, CKW, MPN><<<dim3((MNODE / (8 * MPN)) * NSL), dim3(512), 0, stream>>>(
      L.p, L.q, L.idx, statsL, g1, e1, b1, Wh2, Wl2, b2, g2, L.z, s2b, ss2b);
  if constexpr (DOFIN) {
    // next layer's consumers (knn, node_gemm) apply BN2+ReLU on the fly from z
    bn2params<C><<<dim3(1), dim3(256), 0, stream>>>(s2b, ss2b, g2, e2, L.scl2, L.shf2);
  }
}

// ---------------------------------------------------------------- launch

extern "C" void kernel_launch(void* const* d_in, const int* in_sizes, int n_in,
                              void* d_out, int out_size, void* d_ws, size_t ws_size,
                              hipStream_t stream) {
  const float* x   = (const float*)d_in[0];
  const float* w11 = (const float*)d_in[1];
  const float* b11 = (const float*)d_in[2];
  const float* g11 = (const float*)d_in[3];
  const float* e11 = (const float*)d_in[4];
  const float* w12 = (const float*)d_in[5];
  const float* b12 = (const float*)d_in[6];
  const float* g12 = (const float*)d_in[7];
  const float* e12 = (const float*)d_in[8];
  const float* w21 = (const float*)d_in[9];
  const float* b21 = (const float*)d_in[10];
  const float* g21 = (const float*)d_in[11];
  const float* e21 = (const float*)d_in[12];
  const float* w22 = (const float*)d_in[13];
  const float* b22 = (const float*)d_in[14];
  const float* g22 = (const float*)d_in[15];
  const float* e22 = (const float*)d_in[16];
  const float* w31 = (const float*)d_in[17];
  const float* b31 = (const float*)d_in[18];
  const float* g31 = (const float*)d_in[19];
  const float* e31 = (const float*)d_in[20];
  const float* w32 = (const float*)d_in[21];
  const float* b32 = (const float*)d_in[22];
  const float* g32 = (const float*)d_in[23];
  const float* e32 = (const float*)d_in[24];
  const float* fw1 = (const float*)d_in[25];
  const float* fb1 = (const float*)d_in[26];
  const float* fg1 = (const float*)d_in[27];
  const float* fe1 = (const float*)d_in[28];
  const float* fw2 = (const float*)d_in[29];
  const float* fb2 = (const float*)d_in[30];
  const float* fg2 = (const float*)d_in[31];
  const float* fe2 = (const float*)d_in[32];
  const float* fw3 = (const float*)d_in[33];
  const float* fb3 = (const float*)d_in[34];

  char* wsb = (char*)d_ws;
  size_t o = 0;
  auto alloc = [&](size_t bytes) -> void* {
    void* r = wsb + o;
    o += (bytes + 255) & ~(size_t)255;
    return r;
  };
  LayerPtrs L;
  L.idx   = (int*)  alloc((size_t)MNODE * KK * sizeof(int));
  L.p     = (float*)alloc((size_t)MNODE * 256 * sizeof(float));
  L.q     = (float*)alloc((size_t)MNODE * 256 * sizeof(float));
  L.z     = (float*)alloc((size_t)MNODE * 256 * sizeof(float));
  L.scl2  = (float*)alloc(256 * sizeof(float));
  L.shf2  = (float*)alloc(256 * sizeof(float));
  // per-layer packed weights (filled once by pack_all)
  u16* h12 = (u16*)alloc(64 * 64 * sizeof(u16));
  u16* l12 = (u16*)alloc(64 * 64 * sizeof(u16));
  u16* h22 = (u16*)alloc(128 * 128 * sizeof(u16));
  u16* l22 = (u16*)alloc(128 * 128 * sizeof(u16));
  u16* h32 = (u16*)alloc(256 * 256 * sizeof(u16));
  u16* l32 = (u16*)alloc(256 * 256 * sizeof(u16));
  u16* h21 = (u16*)alloc(64 * 256 * sizeof(u16));
  u16* l21 = (u16*)alloc(64 * 256 * sizeof(u16));
  u16* h31 = (u16*)alloc(128 * 512 * sizeof(u16));
  u16* l31 = (u16*)alloc(128 * 512 * sizeof(u16));
  float* statsAll = (float*)alloc((3 * 8192 + 1024) * sizeof(float));
  float* pooled  = (float*)alloc(128 * 512 * sizeof(float));
  float* t1raw   = (float*)alloc(128 * 256 * sizeof(float));
  float* t2raw   = (float*)alloc(128 * 128 * sizeof(float));

  float* fcstats = statsAll + 3 * 8192;
  float* fs  = fcstats;
  float* fss = fcstats + 256;
  float* gs  = fcstats + 512;
  float* gss = fcstats + 768;

  (void)hipMemsetAsync(statsAll, 0, (3 * 8192 + 1024) * sizeof(float), stream);
  pack_all<<<dim3(656), dim3(256), 0, stream>>>(w12, w22, w32, w21, w31,
      h12, l12, h22, l22, h32, l32, h21, l21, h31, l31);

  // layer 1: raw x input, BN2 params emitted for layer-2 consumers
  run_edgeconv<6, 64, false, true>(x, nullptr, nullptr,
                                   w11, b11, g11, e11, b12, g12, e12,
                                   nullptr, nullptr, h12, l12,
                                   statsAll, L, stream);
  // layer 2: consumes layer-1 z with on-the-fly BN (serial stream: all reads
  // of the old z complete before this layer's gemm2 overwrites it)
  run_edgeconv<64, 128, true, true>(L.z, L.scl2, L.shf2,
                                    nullptr, b21, g21, e21, b22, g22, e22,
                                    h21, l21, h22, l22,
                                    statsAll + 8192, L, stream);
  // layer 3: consumes layer-2 z with on-the-fly BN; its own z goes to fin3_pool
  run_edgeconv<128, 256, true, false>(L.z, L.scl2, L.shf2,
                                      nullptr, b31, g31, e31, b32, g32, e32,
                                      h31, l31, h32, l32,
                                      statsAll + 16384, L, stream);

  // fused finalize(L3) + pool, straight into pooled (h3 never materialized)
  {
    float* s2b3 = statsAll + 16384 + 4096;
    float* ss2b3 = statsAll + 16384 + 6144;
    fin3_pool<<<dim3(BB * 4), dim3(256), 0, stream>>>(L.z, s2b3, ss2b3,
                                                      g32, e32, pooled);
  }
  fc1_fused<<<dim3(BB), dim3(256), 0, stream>>>(pooled, fw1, fb1, t1raw, fs, fss);
  fc2_fused<<<dim3(BB), dim3(256), 0, stream>>>(t1raw, fs, fss, fg1, fe1, fw2, fb2, t2raw, gs, gss);
  fc3_fused<<<dim3(1), dim3(256), 0, stream>>>(t2raw, gs, gss, fg2, fe2, fw3, fb3, (float*)d_out);
}